// Round 13
// baseline (412.661 us; speedup 1.0000x reference)
//
#include <hip/hip_runtime.h>
#include <hip/hip_bf16.h>
#include <math.h>

// Problem constants
#define NBATCH 32
#define LSEQ   96
#define NN     3072
#define HID    128
#define LAT    64
#define EEMB   32

// Workspace layout (float offsets). Total ~6.35 MB.
#define OFF_H      0                          // N x 128 fp32
#define OFF_X      (OFF_H   + NN*HID)         // N x 3
#define OFF_PA     (OFF_X   + NN*3)           // N x 128 fp32 (pa + be1)
#define OFF_AGG    (OFF_PA  + NN*HID)         // N x 128
#define OFF_DX     (OFF_AGG + NN*HID)         // N x 3
#define OFF_ET     (OFF_DX  + NN*3)           // 3*2*128 fp32
#define OFF_ACC    (OFF_ET  + 768)            // 8
#define OFF_NBID   (OFF_ACC + 8)              // N int
#define OFF_CUM    (OFF_NBID + NN)            // 40 int
#define OFF_PBH    (OFF_CUM + 40)             // N x 128 bf16 (as 196608 floats)
#define OFF_BPE    (OFF_PBH + NN*HID/2)       // We2^T  bf16: 3*128*128 -> 24576 floats
#define OFF_BAB    (OFF_BPE + 24576)          // We1[0:256]^T bf16: 3*256*128 -> 49152
#define OFF_BH1    (OFF_BAB + 49152)          // Wh1^T bf16: 3*128*256 -> 49152
#define OFF_BH2    (OFF_BH1 + 49152)          // Wh2^T bf16: 3*128*128 -> 24576
#define OFF_BWO    (OFF_BH2 + 24576)          // Wout^T bf16: 64*128 -> 4096 floats
#define OFF_BWI1   (OFF_BWO + 4096)           // Wi1^T bf16: 128x320 -> 20480 floats
#define OFF_BWI2   (OFF_BWI1 + 20480)         // Wi2^T bf16: 128x128 -> 8192 floats
#define OFF_BWI3   (OFF_BWI2 + 8192)          // Wi3^T bf16: 128x128 -> 8192 floats
#define OFF_CNT    (OFF_BWI3 + 8192)          // 128 uint: [96] = final-election counter

typedef short bf16x8 __attribute__((ext_vector_type(8)));
typedef float f32x4  __attribute__((ext_vector_type(4)));

__device__ __forceinline__ short f2bf(float f) {
    unsigned u = __builtin_bit_cast(unsigned, f);
    unsigned r = (u + 0x7FFFu + ((u >> 16) & 1u)) >> 16;
    return (short)r;
}
__device__ __forceinline__ short2 f2bf2(float a, float b) {
    __hip_bfloat162 h = __float22bfloat162_rn(make_float2(a, b));
    short2 r;
    __builtin_memcpy(&r, &h, sizeof(r));
    return r;
}
__device__ __forceinline__ float bf2f(short s) {
    unsigned u = ((unsigned)(unsigned short)s) << 16;
    return __builtin_bit_cast(float, u);
}
__device__ __forceinline__ float silu(float z) {
    return z * __builtin_amdgcn_rcpf(1.0f + __expf(-z));
}

// --------------------- K0: prep + weight transposes (merged)
__global__ void k0_all(const float* __restrict__ edge_table, const float* __restrict__ We1,
                       const int* __restrict__ lengths, const float* __restrict__ We2,
                       const float* __restrict__ Wh1, const float* __restrict__ Wh2,
                       const float* __restrict__ Wout, const float* __restrict__ Wi1,
                       const float* __restrict__ Wi2, const float* __restrict__ Wi3,
                       float* __restrict__ ws) {
    int tid = threadIdx.x;
    if (blockIdx.x == 1472) {
        int* cum = (int*)(ws + OFF_CUM);
        int* nb  = (int*)(ws + OFF_NBID);
        float* et = ws + OFF_ET;
        if (tid == 0) {
            int s = 0;
            for (int b = 0; b < NBATCH; b++) { cum[b] = s; s += lengths[b]; }
            cum[NBATCH] = s;
        }
        if (tid < 8) ws[OFF_ACC + tid] = 0.0f;
        if (tid < 128) ((unsigned*)(ws + OFF_CNT))[tid] = 0u;
        __syncthreads();
        for (int i = tid; i < NN; i += blockDim.x) {
            int b = NBATCH - 1;
            for (int q = 0; q < NBATCH; q++) { if (i < cum[q + 1]) { b = q; break; } }
            nb[i] = b;
        }
        for (int idx = tid; idx < 3 * 2 * HID; idx += blockDim.x) {
            int c = idx & 127;
            int t = (idx >> 7) & 1;
            int l = idx >> 8;
            const float* w = We1 + (l * 289 + 257) * HID + c;
            const float* e = edge_table + t * EEMB;
            float s = 0.f;
            for (int k = 0; k < EEMB; k++) s += e[k] * w[k * HID];
            et[idx] = s;
        }
        return;
    }
    int idx = blockIdx.x * 256 + tid;   // 0 .. 376831
    short* bpe  = (short*)(ws + OFF_BPE);
    short* bab  = (short*)(ws + OFF_BAB);
    short* bh1  = (short*)(ws + OFF_BH1);
    short* bh2  = (short*)(ws + OFF_BH2);
    short* bwo  = (short*)(ws + OFF_BWO);
    short* bwi1 = (short*)(ws + OFF_BWI1);
    short* bwi2 = (short*)(ws + OFF_BWI2);
    short* bwi3 = (short*)(ws + OFF_BWI3);
    if (idx < 49152) {
        int k = idx & 127, n = (idx >> 7) & 127, l = idx >> 14;
        bpe[idx] = f2bf(We2[(l * 128 + k) * 128 + n]);
    } else if (idx < 147456) {
        int q = idx - 49152;
        int k = q & 127, n = (q >> 7) & 255, l = q >> 15;
        float v = (n < 128) ? We1[(l * 289 + k) * 128 + n]
                            : We1[(l * 289 + 128 + k) * 128 + (n - 128)];
        bab[q] = f2bf(v);
    } else if (idx < 245760) {
        int q = idx - 147456;
        int k = q & 255, n = (q >> 8) & 127, l = q >> 15;
        bh1[q] = f2bf(Wh1[(l * 256 + k) * 128 + n]);
    } else if (idx < 294912) {
        int q = idx - 245760;
        int k = q & 127, n = (q >> 7) & 127, l = q >> 14;
        bh2[q] = f2bf(Wh2[(l * 128 + k) * 128 + n]);
    } else if (idx < 303104) {
        int q = idx - 294912;
        int k = q & 127, n = q >> 7;          // n < 64
        bwo[q] = f2bf(Wout[k * 64 + n]);
    } else if (idx < 344064) {
        int q = idx - 303104;                  // [n<128][k<320]
        int n = q / 320, k = q - n * 320;
        bwi1[q] = f2bf(Wi1[k * 128 + n]);
    } else if (idx < 360448) {
        int q = idx - 344064;
        int k = q & 127, n = q >> 7;
        bwi2[q] = f2bf(Wi2[k * 128 + n]);
    } else if (idx < 376832) {
        int q = idx - 360448;
        int k = q & 127, n = q >> 7;
        bwi3[q] = f2bf(Wi3[k * 128 + n]);
    }
}

// ------------- K1s: init MLP row-split — grid (32, 6), 256 thr, 16 nodes/WG
__global__ void __launch_bounds__(256)
k1s_node_init(const float* __restrict__ H0, const float* __restrict__ X0,
              const float* __restrict__ H1, const float* __restrict__ X1,
              const float* __restrict__ cond, const float* __restrict__ tg,
              const float* __restrict__ bi1, const float* __restrict__ bi2,
              const float* __restrict__ bi3, const float* __restrict__ be1,
              const int* __restrict__ gmask, float* __restrict__ ws) {
    __shared__ short u1[16 * 136];
    __shared__ short u2[16 * 136];
    int rowbase = blockIdx.x * 96 + blockIdx.y * 16;
    int tid = threadIdx.x;
    int w = tid >> 6, lane = tid & 63;
    int quad = lane >> 4, lp = lane & 15;
    int nodeA = rowbase + lp;
    const int* nb = (const int*)(ws + OFF_NBID);
    float t = tg[nb[nodeA]];
    float u = (gmask[nodeA] != 0) ? t : 1.0f;

    if (tid < 48) {
        int node = rowbase + tid / 3, d = tid % 3;
        float tn = tg[nb[node]];
        float un = (gmask[node] != 0) ? tn : 1.0f;
        ws[OFF_X + (size_t)node * 3 + d] =
            (1.0f - un) * X0[(size_t)node * 3 + d] + un * X1[(size_t)node * 3 + d];
    }

    const short* bwi1 = (const short*)(ws + OFF_BWI1);
    const short* bwi2 = (const short*)(ws + OFF_BWI2);
    const short* bwi3 = (const short*)(ws + OFF_BWI3);
    const short* bab  = (const short*)(ws + OFF_BAB);   // l = 0

    // ---- GEMM1: K=320
    f32x4 acc[2];
    acc[0] = (f32x4){0.f, 0.f, 0.f, 0.f};
    acc[1] = (f32x4){0.f, 0.f, 0.f, 0.f};
    for (int s = 0; s < 10; s++) {
        int kb = s * 32 + quad * 8;
        float z[8];
        if (kb < 64) {
            const float* h0 = H0 + (size_t)nodeA * 64 + kb;
            const float* h1 = H1 + (size_t)nodeA * 64 + kb;
            #pragma unroll
            for (int e = 0; e < 8; e++) z[e] = (1.0f - u) * h0[e] + u * h1[e];
        } else if (kb < 192) {
            const float* cp = cond + (size_t)nodeA * 128 + (kb - 64);
            #pragma unroll
            for (int e = 0; e < 8; e++) z[e] = cp[e];
        } else if (kb < 256) {
            #pragma unroll
            for (int e = 0; e < 8; e++) {
                float c = (float)(kb - 192 + e);
                float fr = __expf(-9.2103403719761836f * c / 63.0f);
                z[e] = __sinf(t * fr);
            }
        } else {
            #pragma unroll
            for (int e = 0; e < 8; e++) {
                float c = (float)(kb - 256 + e);
                float fr = __expf(-9.2103403719761836f * c / 63.0f);
                z[e] = __cosf(t * fr);
            }
        }
        bf16x8 af;
        #pragma unroll
        for (int e = 0; e < 8; e += 2) {
            short2 p = f2bf2(z[e], z[e + 1]);
            af[e] = p.x; af[e + 1] = p.y;
        }
        #pragma unroll
        for (int i = 0; i < 2; i++) {
            int ct = 2 * w + i;
            bf16x8 bf = *(const bf16x8*)(bwi1 + (size_t)(16 * ct + lp) * 320 + kb);
            acc[i] = __builtin_amdgcn_mfma_f32_16x16x32_bf16(af, bf, acc[i], 0, 0, 0);
        }
    }
    #pragma unroll
    for (int i = 0; i < 2; i++) {
        int ch = 16 * (2 * w + i) + lp;
        float bb1 = bi1[ch];
        #pragma unroll
        for (int r = 0; r < 4; r++)
            u1[(quad * 4 + r) * 136 + ch] = f2bf(fmaxf(acc[i][r] + bb1, 0.0f));
    }
    __syncthreads();

    // ---- GEMM2: K=128
    acc[0] = (f32x4){0.f, 0.f, 0.f, 0.f};
    acc[1] = (f32x4){0.f, 0.f, 0.f, 0.f};
    #pragma unroll
    for (int s = 0; s < 4; s++) {
        int kb = s * 32 + quad * 8;
        bf16x8 af = *(const bf16x8*)(u1 + lp * 136 + kb);
        #pragma unroll
        for (int i = 0; i < 2; i++) {
            int ct = 2 * w + i;
            bf16x8 bf = *(const bf16x8*)(bwi2 + (size_t)(16 * ct + lp) * 128 + kb);
            acc[i] = __builtin_amdgcn_mfma_f32_16x16x32_bf16(af, bf, acc[i], 0, 0, 0);
        }
    }
    #pragma unroll
    for (int i = 0; i < 2; i++) {
        int ch = 16 * (2 * w + i) + lp;
        float bb2 = bi2[ch];
        #pragma unroll
        for (int r = 0; r < 4; r++)
            u2[(quad * 4 + r) * 136 + ch] = f2bf(fmaxf(acc[i][r] + bb2, 0.0f));
    }
    __syncthreads();

    // ---- GEMM3: K=128 -> h (no relu)
    acc[0] = (f32x4){0.f, 0.f, 0.f, 0.f};
    acc[1] = (f32x4){0.f, 0.f, 0.f, 0.f};
    #pragma unroll
    for (int s = 0; s < 4; s++) {
        int kb = s * 32 + quad * 8;
        bf16x8 af = *(const bf16x8*)(u2 + lp * 136 + kb);
        #pragma unroll
        for (int i = 0; i < 2; i++) {
            int ct = 2 * w + i;
            bf16x8 bf = *(const bf16x8*)(bwi3 + (size_t)(16 * ct + lp) * 128 + kb);
            acc[i] = __builtin_amdgcn_mfma_f32_16x16x32_bf16(af, bf, acc[i], 0, 0, 0);
        }
    }
    #pragma unroll
    for (int i = 0; i < 2; i++) {
        int ch = 16 * (2 * w + i) + lp;
        float bb3 = bi3[ch];
        #pragma unroll
        for (int r = 0; r < 4; r++) {
            int row = quad * 4 + r;
            float h = acc[i][r] + bb3;
            ws[OFF_H + (size_t)(rowbase + row) * 128 + ch] = h;
            u1[row * 136 + ch] = f2bf(h);
        }
    }
    __syncthreads();

    // ---- GEMM4: pa/pb layer 0, N=256 (ct4 = 4w..4w+3)
    f32x4 acc4[4];
    #pragma unroll
    for (int i = 0; i < 4; i++) acc4[i] = (f32x4){0.f, 0.f, 0.f, 0.f};
    #pragma unroll
    for (int s = 0; s < 4; s++) {
        int kb = s * 32 + quad * 8;
        bf16x8 af = *(const bf16x8*)(u1 + lp * 136 + kb);
        #pragma unroll
        for (int i = 0; i < 4; i++) {
            int ct4 = 4 * w + i;
            bf16x8 bf = *(const bf16x8*)(bab + (size_t)(16 * ct4 + lp) * 128 + kb);
            acc4[i] = __builtin_amdgcn_mfma_f32_16x16x32_bf16(af, bf, acc4[i], 0, 0, 0);
        }
    }
    short* pbh = (short*)(ws + OFF_PBH);
    #pragma unroll
    for (int i = 0; i < 4; i++) {
        int ct4 = 4 * w + i;
        #pragma unroll
        for (int r = 0; r < 4; r++) {
            int node = rowbase + quad * 4 + r;
            if (ct4 < 8) {
                int ch = 16 * ct4 + lp;
                ws[OFF_PA + (size_t)node * 128 + ch] = acc4[i][r] + be1[ch];
            } else {
                int ch = 16 * (ct4 - 8) + lp;
                pbh[(size_t)node * 128 + ch] = f2bf(acc4[i][r]);
            }
        }
    }
}

// -------- K3c2: edge kernel — TWO TARGETS INTERLEAVED PER WAVE (2x ILP).
// g-pairs share pbv and B-fragment loads; two independent acc chains per wave
// cover the ds_read->silu->cvt->MFMA latency that R8..R12 showed binding.
#define KG 4
#define SMC_BS    0        // short[2048][8] swizzled = 32768
#define SMC_AGG   32768    // float[6*128] = 3072
#define SMC_PA    35840    // float[KG*128] = 2048
#define SMC_ET    37888    // float[2*128] = 1024
#define SMC_WC    38912    // float[128] = 512
#define SMC_BE2   39424    // float[128] = 512
#define SMC_WX    39936    // float[128] = 512
#define SMC_COEF  40448    // float[96] = 384
#define SMC_XT    40832    // float[12] = 48
#define SMC_CI    40880    // int[4] = 16  -> total 40896
__global__ void __launch_bounds__(384)
k3c2_edge(const float* __restrict__ We1, const float* __restrict__ Wx,
          const float* __restrict__ be2, const int* __restrict__ chain,
          int l, float* __restrict__ ws) {
    __shared__ __align__(16) char smem[40896];
    short* bS    = (short*)(smem + SMC_BS);
    float* aggP  = (float*)(smem + SMC_AGG);
    float* paS   = (float*)(smem + SMC_PA);
    float* etS   = (float*)(smem + SMC_ET);
    float* wcS   = (float*)(smem + SMC_WC);
    float* be2S  = (float*)(smem + SMC_BE2);
    float* wxS   = (float*)(smem + SMC_WX);
    float* coefS = (float*)(smem + SMC_COEF);
    float* xT    = (float*)(smem + SMC_XT);
    int*   ciS   = (int*)  (smem + SMC_CI);

    int tid = threadIdx.x;
    int i0 = blockIdx.x * KG;
    int colbase = (i0 / 96) * 96;
    const float* Xc = ws + OFF_X;

    // ---- stage: swizzled B + per-target pa + et + wc + be2/wx
    {
        const short* bpe = (const short*)(ws + OFF_BPE) + (size_t)l * 128 * 128;
        for (int idx = tid; idx < 2048; idx += 384) {
            int t = idx >> 8, s = (idx >> 6) & 3, ln = idx & 63;
            int lq = ln >> 4, lpp = ln & 15;
            *(bf16x8*)(bS + idx * 8) =
                *(const bf16x8*)(bpe + (size_t)(16 * t + lpp) * 128 + s * 32 + lq * 8);
        }
        if (tid < 128) {
            #pragma unroll
            for (int g = 0; g < KG; g++)
                paS[g * 128 + tid] = ws[OFF_PA + (size_t)(i0 + g) * 128 + tid];
            etS[tid]       = ws[OFF_ET + l * 256 + tid];
            etS[128 + tid] = ws[OFF_ET + l * 256 + 128 + tid];
            wcS[tid]       = We1[(l * 289 + 256) * 128 + tid];
            be2S[tid]      = be2[l * 128 + tid];
            wxS[tid]       = Wx[l * 128 + tid];
        }
        if (tid < KG * 3) xT[tid] = Xc[(size_t)(i0 + tid / 3) * 3 + tid % 3];
        if (tid < KG) ciS[tid] = chain[i0 + tid];
    }

    int w = tid >> 6, lane = tid & 63;
    int quad = lane >> 4, lp = lane & 15;
    int jA = 16 * w + lp;                       // lane's fixed source row
    const short* pbrow = (const short*)(ws + OFF_PBH) + (size_t)(colbase + jA) * 128;
    bf16x8 pbv[4];
    #pragma unroll
    for (int s = 0; s < 4; s++) pbv[s] = *(const bf16x8*)(pbrow + s * 32 + quad * 8);
    float xr0 = Xc[(size_t)(colbase + jA) * 3 + 0];
    float xr1 = Xc[(size_t)(colbase + jA) * 3 + 1];
    float xr2 = Xc[(size_t)(colbase + jA) * 3 + 2];
    int cj = chain[colbase + jA];
    // epilogue x hoists (waves 0..2 only use them)
    float ex0 = 0.f, ex1 = 0.f;
    if (w < 3) {
        ex0 = Xc[(size_t)(colbase + lane) * 3 + w];
        if (lane < 32) ex1 = Xc[(size_t)(colbase + lane + 64) * 3 + w];
    }
    __syncthreads();

    for (int gp = 0; gp < KG; gp += 2) {
        int gA = gp, gB = gp + 1;
        float rxA = xT[gA * 3 + 0] - xr0, ryA = xT[gA * 3 + 1] - xr1, rzA = xT[gA * 3 + 2] - xr2;
        float rxB = xT[gB * 3 + 0] - xr0, ryB = xT[gB * 3 + 1] - xr1, rzB = xT[gB * 3 + 2] - xr2;
        float d2A = rxA * rxA + ryA * ryA + rzA * rzA;
        float d2B = rxB * rxB + ryB * ryB + rzB * rzB;
        const float* etA = etS + ((cj != ciS[gA]) ? 128 : 0);
        const float* etB = etS + ((cj != ciS[gB]) ? 128 : 0);
        const float* paA = paS + gA * 128;
        const float* paB = paS + gB * 128;

        f32x4 accA[8], accB[8];
        #pragma unroll
        for (int t = 0; t < 8; t++) {
            accA[t] = (f32x4){0.f, 0.f, 0.f, 0.f};
            accB[t] = (f32x4){0.f, 0.f, 0.f, 0.f};
        }

        #pragma unroll
        for (int s = 0; s < 4; s++) {
            int kb = s * 32 + quad * 8;
            bf16x8 afA, afB;
            #pragma unroll
            for (int e = 0; e < 8; e += 2) {
                float pb0 = bf2f(pbv[s][e]), pb1 = bf2f(pbv[s][e + 1]);
                float wc0 = wcS[kb + e], wc1 = wcS[kb + e + 1];
                float zA0 = silu(paA[kb + e]     + etA[kb + e]     + pb0 + d2A * wc0);
                float zA1 = silu(paA[kb + e + 1] + etA[kb + e + 1] + pb1 + d2A * wc1);
                float zB0 = silu(paB[kb + e]     + etB[kb + e]     + pb0 + d2B * wc0);
                float zB1 = silu(paB[kb + e + 1] + etB[kb + e + 1] + pb1 + d2B * wc1);
                short2 pA = f2bf2(zA0, zA1);
                short2 pB = f2bf2(zB0, zB1);
                afA[e] = pA.x; afA[e + 1] = pA.y;
                afB[e] = pB.x; afB[e + 1] = pB.y;
            }
            #pragma unroll
            for (int t = 0; t < 8; t++) {
                bf16x8 bf = *(const bf16x8*)(bS + ((t * 4 + s) * 64 + lane) * 8);
                accA[t] = __builtin_amdgcn_mfma_f32_16x16x32_bf16(afA, bf, accA[t], 0, 0, 0);
                accB[t] = __builtin_amdgcn_mfma_f32_16x16x32_bf16(afB, bf, accB[t], 0, 0, 0);
            }
        }

        // ---- epilogue, target A then target B (aggP/coefS reused)
        #pragma unroll
        for (int half = 0; half < 2; half++) {
            int g = (half == 0) ? gA : gB;
            f32x4* acc = (half == 0) ? accA : accB;
            float cp[4] = {0.f, 0.f, 0.f, 0.f};
            #pragma unroll
            for (int t = 0; t < 8; t++) {
                int ch = 16 * t + lp;
                float bb = be2S[ch];
                float wx = wxS[ch];
                float ag = 0.f;
                #pragma unroll
                for (int r = 0; r < 4; r++) {
                    float m2 = silu(acc[t][r] + bb);
                    ag += m2;
                    cp[r] += m2 * wx;
                }
                ag += __shfl_xor(ag, 16);
                ag += __shfl_xor(ag, 32);
                if (lane < 16) aggP[w * 128 + ch] = ag;
            }
            #pragma unroll
            for (int r = 0; r < 4; r++) {
                float v = cp[r];
                v += __shfl_xor(v, 1);
                v += __shfl_xor(v, 2);
                v += __shfl_xor(v, 4);
                v += __shfl_xor(v, 8);
                if (lp == 0) coefS[16 * w + quad * 4 + r] = v;
            }
            __syncthreads();

            if (tid < 128) {
                float s = 0.f;
                #pragma unroll
                for (int q = 0; q < 6; q++) s += aggP[q * 128 + tid];
                ws[OFF_AGG + (size_t)(i0 + g) * 128 + tid] = s;
            }
            if (w < 3) {
                float v = (xT[g * 3 + w] - ex0) * coefS[lane];
                if (lane < 32) v += (xT[g * 3 + w] - ex1) * coefS[lane + 64];
                #pragma unroll
                for (int o = 32; o > 0; o >>= 1) v += __shfl_down(v, o);
                if (lane == 0) ws[OFF_DX + (size_t)(i0 + g) * 3 + w] = v;
            }
            __syncthreads();
        }
    }
}

// ----- K4s8: node update row-split — grid (32, 6), 512 thr (8 waves),
// 16 nodes/WG; each wave owns ONE col-tile (halves per-wave MFMA chain).
__global__ void __launch_bounds__(512)
k4s8_node_post(const float* __restrict__ bh1, const float* __restrict__ bh2,
               const float* __restrict__ be1, const float* __restrict__ bout,
               const float* __restrict__ H0, const float* __restrict__ X0,
               const float* __restrict__ H1, const float* __restrict__ X1,
               const int* __restrict__ gmask, const int* __restrict__ shiftp,
               int l, float* __restrict__ ws, float* __restrict__ out) {
    __shared__ short uS[16 * 136];
    __shared__ short hS[16 * 136];
    __shared__ float redE[8], redN[8];
    __shared__ float sxp, sxn, scnt;
    int rowbase = blockIdx.x * 96 + blockIdx.y * 16;
    int tid = threadIdx.x;
    int w = tid >> 6, lane = tid & 63;          // w = 0..7
    int quad = lane >> 4, lp = lane & 15;
    int nodeA = rowbase + lp;
    const short* b1 = (const short*)(ws + OFF_BH1) + (size_t)l * 128 * 256;
    const short* b2 = (const short*)(ws + OFF_BH2) + (size_t)l * 128 * 128;

    if (tid == 0) { sxp = 0.f; sxn = 0.f; scnt = 0.f; }
    if (tid < 48) {
        int node = rowbase + tid / 3, d = tid % 3;
        ws[OFF_X + (size_t)node * 3 + d] += ws[OFF_DX + (size_t)node * 3 + d];
    }

    // ---- GEMM1: [h|agg] K=256 -> u (silu); ct = w (one tile per wave)
    f32x4 acc = (f32x4){0.f, 0.f, 0.f, 0.f};
    #pragma unroll
    for (int s = 0; s < 8; s++) {
        int kb = s * 32 + quad * 8;
        const float* src = (kb < 128) ? (ws + OFF_H + (size_t)nodeA * 128 + kb)
                                      : (ws + OFF_AGG + (size_t)nodeA * 128 + (kb - 128));
        bf16x8 af;
        #pragma unroll
        for (int e = 0; e < 8; e += 2) {
            short2 p = f2bf2(src[e], src[e + 1]);
            af[e] = p.x; af[e + 1] = p.y;
        }
        bf16x8 bf = *(const bf16x8*)(b1 + (size_t)(16 * w + lp) * 256 + kb);
        acc = __builtin_amdgcn_mfma_f32_16x16x32_bf16(af, bf, acc, 0, 0, 0);
    }
    {
        int ch = 16 * w + lp;
        float bb1 = bh1[l * 128 + ch];
        #pragma unroll
        for (int r = 0; r < 4; r++)
            uS[(quad * 4 + r) * 136 + ch] = f2bf(silu(acc[r] + bb1));
    }
    __syncthreads();

    // ---- GEMM2: u @ Wh2 -> h += ; hS = bf16(h); ct = w
    acc = (f32x4){0.f, 0.f, 0.f, 0.f};
    #pragma unroll
    for (int s = 0; s < 4; s++) {
        int kb = s * 32 + quad * 8;
        bf16x8 af = *(const bf16x8*)(uS + lp * 136 + kb);
        bf16x8 bf = *(const bf16x8*)(b2 + (size_t)(16 * w + lp) * 128 + kb);
        acc = __builtin_amdgcn_mfma_f32_16x16x32_bf16(af, bf, acc, 0, 0, 0);
    }
    {
        int ch = 16 * w + lp;
        float bb2 = bh2[l * 128 + ch];
        #pragma unroll
        for (int r = 0; r < 4; r++) {
            int row = quad * 4 + r;
            size_t off = OFF_H + (size_t)(rowbase + row) * 128 + ch;
            float h = ws[off] + acc[r] + bb2;
            ws[off] = h;
            hS[row * 136 + ch] = f2bf(h);
        }
    }
    __syncthreads();

    if (l < 2) {
        // ---- GEMM3: pa/pb for layer l+1, N=256 (ct4 = 2w+i)
        const short* bab = (const short*)(ws + OFF_BAB) + (size_t)(l + 1) * 256 * 128;
        f32x4 acc4[2];
        acc4[0] = (f32x4){0.f, 0.f, 0.f, 0.f};
        acc4[1] = (f32x4){0.f, 0.f, 0.f, 0.f};
        #pragma unroll
        for (int s = 0; s < 4; s++) {
            int kb = s * 32 + quad * 8;
            bf16x8 af = *(const bf16x8*)(hS + lp * 136 + kb);
            #pragma unroll
            for (int i = 0; i < 2; i++) {
                int ct4 = 2 * w + i;
                bf16x8 bf = *(const bf16x8*)(bab + (size_t)(16 * ct4 + lp) * 128 + kb);
                acc4[i] = __builtin_amdgcn_mfma_f32_16x16x32_bf16(af, bf, acc4[i], 0, 0, 0);
            }
        }
        short* pbh = (short*)(ws + OFF_PBH);
        #pragma unroll
        for (int i = 0; i < 2; i++) {
            int ct4 = 2 * w + i;
            #pragma unroll
            for (int r = 0; r < 4; r++) {
                int node = rowbase + quad * 4 + r;
                if (ct4 < 8) {
                    int ch = 16 * ct4 + lp;
                    ws[OFF_PA + (size_t)node * 128 + ch] = acc4[i][r] + be1[(l + 1) * 128 + ch];
                } else {
                    int ch = 16 * (ct4 - 8) + lp;
                    pbh[(size_t)node * 128 + ch] = f2bf(acc4[i][r]);
                }
            }
        }
    } else {
        // ---- GEMM3: v = h @ Wout^T (N=64: waves 0..3) + loss + final out
        const short* bwo = (const short*)(ws + OFF_BWO);
        int s = shiftp[0] % NN; if (s < 0) s += NN;
        float ep = 0.f, en = 0.f;
        if (w < 4) {
            f32x4 accv = (f32x4){0.f, 0.f, 0.f, 0.f};
            #pragma unroll
            for (int ss = 0; ss < 4; ss++) {
                int kb = ss * 32 + quad * 8;
                bf16x8 af = *(const bf16x8*)(hS + lp * 136 + kb);
                bf16x8 bf = *(const bf16x8*)(bwo + (size_t)(16 * w + lp) * 128 + kb);
                accv = __builtin_amdgcn_mfma_f32_16x16x32_bf16(af, bf, accv, 0, 0, 0);
            }
            int col = 16 * w + lp;
            float bo = bout[col];
            #pragma unroll
            for (int r = 0; r < 4; r++) {
                int row = rowbase + quad * 4 + r;
                if (gmask[row] != 0) {
                    int ip = row + s; if (ip >= NN) ip -= NN;
                    float v  = accv[r] + bo;
                    float tp = H1[(size_t)row * 64 + col] - H0[(size_t)row * 64 + col];
                    float tn = H1[(size_t)ip * 64 + col]  - H0[(size_t)ip * 64 + col];
                    float dp = v - tp, dn = v - tn;
                    ep += dp * dp;
                    en += dn * dn;
                }
            }
            #pragma unroll
            for (int o = 1; o < 64; o <<= 1) {
                ep += __shfl_xor(ep, o);
                en += __shfl_xor(en, o);
            }
        }
        if (lane == 0) { redE[w] = (w < 4) ? ep : 0.f; redN[w] = (w < 4) ? en : 0.f; }

        if (tid < 16) {
            int node = rowbase + tid;
            if (gmask[node] != 0) {
                int ip = node + s; if (ip >= NN) ip -= NN;
                float xp = 0.f, xn = 0.f;
                #pragma unroll
                for (int d = 0; d < 3; d++) {
                    float xv  = ws[OFF_X + (size_t)node * 3 + d];
                    float tpx = X1[(size_t)node * 3 + d] - X0[(size_t)node * 3 + d];
                    float tnx = X1[(size_t)ip * 3 + d]   - X0[(size_t)ip * 3 + d];
                    xp += (xv - tpx) * (xv - tpx);
                    xn += (xv - tnx) * (xv - tnx);
                }
                atomicAdd(&sxp, xp);
                atomicAdd(&sxn, xn);
                atomicAdd(&scnt, 1.0f);
            }
        }
        __syncthreads();
        if (tid == 0) {
            float eT = 0.f, nT = 0.f;
            #pragma unroll
            for (int q = 0; q < 8; q++) { eT += redE[q]; nT += redN[q]; }
            float* acc0 = ws + OFF_ACC;
            atomicAdd(acc0 + 0, eT);
            atomicAdd(acc0 + 2, nT);
            atomicAdd(acc0 + 1, sxp);
            atomicAdd(acc0 + 3, sxn);
            atomicAdd(acc0 + 4, scnt);
            // ---- final election among the 192 l==2 WGs: write out
            __threadfence();
            unsigned o2 = atomicAdd((unsigned*)(ws + OFF_CNT) + 96, 1u);
            if (o2 == 191u) {
                __threadfence();
                float a0 = atomicAdd(acc0 + 0, 0.0f);
                float a1 = atomicAdd(acc0 + 1, 0.0f);
                float a2 = atomicAdd(acc0 + 2, 0.0f);
                float a3 = atomicAdd(acc0 + 3, 0.0f);
                float a4 = atomicAdd(acc0 + 4, 0.0f);
                float msum = a4 + 1e-8f;
                float lhp = a0 / msum, lxp = a1 / msum;
                float lhn = a2 / msum, lxn = a3 / msum;
                out[0] = lhp - 0.05f * lhn;
                out[1] = lxp - 0.05f * lxn;
                out[2] = lhp;
                out[3] = lxp;
                out[4] = lhn;
                out[5] = lxn;
            }
        }
    }
}

extern "C" void kernel_launch(void* const* d_in, const int* in_sizes, int n_in,
                              void* d_out, int out_size, void* d_ws, size_t ws_size,
                              hipStream_t stream) {
    (void)in_sizes; (void)n_in; (void)out_size; (void)ws_size;
    const float* H0   = (const float*)d_in[0];
    const float* X0   = (const float*)d_in[1];
    const float* H1   = (const float*)d_in[2];
    const float* X1   = (const float*)d_in[3];
    const float* cond = (const float*)d_in[4];
    const float* tg   = (const float*)d_in[5];
    const float* Wi1  = (const float*)d_in[6];
    const float* bi1  = (const float*)d_in[7];
    const float* Wi2  = (const float*)d_in[8];
    const float* bi2  = (const float*)d_in[9];
    const float* Wi3  = (const float*)d_in[10];
    const float* bi3  = (const float*)d_in[11];
    const float* etab = (const float*)d_in[12];
    const float* We1  = (const float*)d_in[13];
    const float* be1  = (const float*)d_in[14];
    const float* We2  = (const float*)d_in[15];
    const float* be2  = (const float*)d_in[16];
    const float* Wx   = (const float*)d_in[17];
    const float* Wh1  = (const float*)d_in[18];
    const float* bh1  = (const float*)d_in[19];
    const float* Wh2  = (const float*)d_in[20];
    const float* bh2  = (const float*)d_in[21];
    const float* Wout = (const float*)d_in[22];
    const float* bout = (const float*)d_in[23];
    const int* chain   = (const int*)d_in[25];
    const int* gmask   = (const int*)d_in[26];
    const int* lengths = (const int*)d_in[27];
    const int* shiftp  = (const int*)d_in[28];
    float* ws  = (float*)d_ws;
    float* out = (float*)d_out;

    k0_all<<<1473, 256, 0, stream>>>(etab, We1, lengths, We2, Wh1, Wh2,
                                     Wout, Wi1, Wi2, Wi3, ws);
    k1s_node_init<<<dim3(NBATCH, 6), 256, 0, stream>>>(H0, X0, H1, X1, cond, tg,
                                                       bi1, bi2, bi3, be1, gmask, ws);
    for (int l = 0; l < 3; l++) {
        k3c2_edge<<<NN / KG, 384, 0, stream>>>(We1, Wx, be2, chain, l, ws);
        k4s8_node_post<<<dim3(NBATCH, 6), 512, 0, stream>>>(bh1, bh2, be1, bout,
                                                            H0, X0, H1, X1, gmask, shiftp,
                                                            l, ws, out);
    }
}

// Round 14
// 392.172 us; speedup vs baseline: 1.0522x; 1.0522x over previous
//
#include <hip/hip_runtime.h>
#include <hip/hip_bf16.h>
#include <math.h>

// Problem constants
#define NBATCH 32
#define LSEQ   96
#define NN     3072
#define HID    128
#define LAT    64
#define EEMB   32

// Workspace layout (float offsets). Total ~6.35 MB.
#define OFF_H      0                          // N x 128 fp32
#define OFF_X      (OFF_H   + NN*HID)         // N x 3
#define OFF_PA     (OFF_X   + NN*3)           // N x 128 fp32 (pa + be1)
#define OFF_AGG    (OFF_PA  + NN*HID)         // N x 128
#define OFF_DX     (OFF_AGG + NN*HID)         // N x 3
#define OFF_ET     (OFF_DX  + NN*3)           // 3*2*128 fp32
#define OFF_ACC    (OFF_ET  + 768)            // 8
#define OFF_NBID   (OFF_ACC + 8)              // N int
#define OFF_CUM    (OFF_NBID + NN)            // 40 int
#define OFF_PBH    (OFF_CUM + 40)             // N x 128 bf16 (as 196608 floats)
#define OFF_BPE    (OFF_PBH + NN*HID/2)       // We2^T  bf16: 3*128*128 -> 24576 floats
#define OFF_BAB    (OFF_BPE + 24576)          // We1[0:256]^T bf16: 3*256*128 -> 49152
#define OFF_BH1    (OFF_BAB + 49152)          // Wh1^T bf16: 3*128*256 -> 49152
#define OFF_BH2    (OFF_BH1 + 49152)          // Wh2^T bf16: 3*128*128 -> 24576
#define OFF_BWO    (OFF_BH2 + 24576)          // Wout^T bf16: 64*128 -> 4096 floats
#define OFF_BWI1   (OFF_BWO + 4096)           // Wi1^T bf16: 128x320 -> 20480 floats
#define OFF_BWI2   (OFF_BWI1 + 20480)         // Wi2^T bf16: 128x128 -> 8192 floats
#define OFF_BWI3   (OFF_BWI2 + 8192)          // Wi3^T bf16: 128x128 -> 8192 floats
#define OFF_CNT    (OFF_BWI3 + 8192)          // 128 uint: [96] = final-election counter

typedef short bf16x8 __attribute__((ext_vector_type(8)));
typedef float f32x4  __attribute__((ext_vector_type(4)));

__device__ __forceinline__ short f2bf(float f) {
    unsigned u = __builtin_bit_cast(unsigned, f);
    unsigned r = (u + 0x7FFFu + ((u >> 16) & 1u)) >> 16;
    return (short)r;
}
__device__ __forceinline__ short2 f2bf2(float a, float b) {
    __hip_bfloat162 h = __float22bfloat162_rn(make_float2(a, b));
    short2 r;
    __builtin_memcpy(&r, &h, sizeof(r));
    return r;
}
__device__ __forceinline__ float bf2f(short s) {
    unsigned u = ((unsigned)(unsigned short)s) << 16;
    return __builtin_bit_cast(float, u);
}
__device__ __forceinline__ float silu(float z) {
    return z * __builtin_amdgcn_rcpf(1.0f + __expf(-z));
}

// --------------------- K0: prep + weight transposes (merged)
__global__ void k0_all(const float* __restrict__ edge_table, const float* __restrict__ We1,
                       const int* __restrict__ lengths, const float* __restrict__ We2,
                       const float* __restrict__ Wh1, const float* __restrict__ Wh2,
                       const float* __restrict__ Wout, const float* __restrict__ Wi1,
                       const float* __restrict__ Wi2, const float* __restrict__ Wi3,
                       float* __restrict__ ws) {
    int tid = threadIdx.x;
    if (blockIdx.x == 1472) {
        int* cum = (int*)(ws + OFF_CUM);
        int* nb  = (int*)(ws + OFF_NBID);
        float* et = ws + OFF_ET;
        if (tid == 0) {
            int s = 0;
            for (int b = 0; b < NBATCH; b++) { cum[b] = s; s += lengths[b]; }
            cum[NBATCH] = s;
        }
        if (tid < 8) ws[OFF_ACC + tid] = 0.0f;
        if (tid < 128) ((unsigned*)(ws + OFF_CNT))[tid] = 0u;
        __syncthreads();
        for (int i = tid; i < NN; i += blockDim.x) {
            int b = NBATCH - 1;
            for (int q = 0; q < NBATCH; q++) { if (i < cum[q + 1]) { b = q; break; } }
            nb[i] = b;
        }
        for (int idx = tid; idx < 3 * 2 * HID; idx += blockDim.x) {
            int c = idx & 127;
            int t = (idx >> 7) & 1;
            int l = idx >> 8;
            const float* w = We1 + (l * 289 + 257) * HID + c;
            const float* e = edge_table + t * EEMB;
            float s = 0.f;
            for (int k = 0; k < EEMB; k++) s += e[k] * w[k * HID];
            et[idx] = s;
        }
        return;
    }
    int idx = blockIdx.x * 256 + tid;   // 0 .. 376831
    short* bpe  = (short*)(ws + OFF_BPE);
    short* bab  = (short*)(ws + OFF_BAB);
    short* bh1  = (short*)(ws + OFF_BH1);
    short* bh2  = (short*)(ws + OFF_BH2);
    short* bwo  = (short*)(ws + OFF_BWO);
    short* bwi1 = (short*)(ws + OFF_BWI1);
    short* bwi2 = (short*)(ws + OFF_BWI2);
    short* bwi3 = (short*)(ws + OFF_BWI3);
    if (idx < 49152) {
        int k = idx & 127, n = (idx >> 7) & 127, l = idx >> 14;
        bpe[idx] = f2bf(We2[(l * 128 + k) * 128 + n]);
    } else if (idx < 147456) {
        int q = idx - 49152;
        int k = q & 127, n = (q >> 7) & 255, l = q >> 15;
        float v = (n < 128) ? We1[(l * 289 + k) * 128 + n]
                            : We1[(l * 289 + 128 + k) * 128 + (n - 128)];
        bab[q] = f2bf(v);
    } else if (idx < 245760) {
        int q = idx - 147456;
        int k = q & 255, n = (q >> 8) & 127, l = q >> 15;
        bh1[q] = f2bf(Wh1[(l * 256 + k) * 128 + n]);
    } else if (idx < 294912) {
        int q = idx - 245760;
        int k = q & 127, n = (q >> 7) & 127, l = q >> 14;
        bh2[q] = f2bf(Wh2[(l * 128 + k) * 128 + n]);
    } else if (idx < 303104) {
        int q = idx - 294912;
        int k = q & 127, n = q >> 7;          // n < 64
        bwo[q] = f2bf(Wout[k * 64 + n]);
    } else if (idx < 344064) {
        int q = idx - 303104;                  // [n<128][k<320]
        int n = q / 320, k = q - n * 320;
        bwi1[q] = f2bf(Wi1[k * 128 + n]);
    } else if (idx < 360448) {
        int q = idx - 344064;
        int k = q & 127, n = q >> 7;
        bwi2[q] = f2bf(Wi2[k * 128 + n]);
    } else if (idx < 376832) {
        int q = idx - 360448;
        int k = q & 127, n = q >> 7;
        bwi3[q] = f2bf(Wi3[k * 128 + n]);
    }
}

// ------------- K1s: init MLP row-split — grid (32, 6), 256 thr, 16 nodes/WG
__global__ void __launch_bounds__(256)
k1s_node_init(const float* __restrict__ H0, const float* __restrict__ X0,
              const float* __restrict__ H1, const float* __restrict__ X1,
              const float* __restrict__ cond, const float* __restrict__ tg,
              const float* __restrict__ bi1, const float* __restrict__ bi2,
              const float* __restrict__ bi3, const float* __restrict__ be1,
              const int* __restrict__ gmask, float* __restrict__ ws) {
    __shared__ short u1[16 * 136];
    __shared__ short u2[16 * 136];
    int rowbase = blockIdx.x * 96 + blockIdx.y * 16;
    int tid = threadIdx.x;
    int w = tid >> 6, lane = tid & 63;
    int quad = lane >> 4, lp = lane & 15;
    int nodeA = rowbase + lp;
    const int* nb = (const int*)(ws + OFF_NBID);
    float t = tg[nb[nodeA]];
    float u = (gmask[nodeA] != 0) ? t : 1.0f;

    if (tid < 48) {
        int node = rowbase + tid / 3, d = tid % 3;
        float tn = tg[nb[node]];
        float un = (gmask[node] != 0) ? tn : 1.0f;
        ws[OFF_X + (size_t)node * 3 + d] =
            (1.0f - un) * X0[(size_t)node * 3 + d] + un * X1[(size_t)node * 3 + d];
    }

    const short* bwi1 = (const short*)(ws + OFF_BWI1);
    const short* bwi2 = (const short*)(ws + OFF_BWI2);
    const short* bwi3 = (const short*)(ws + OFF_BWI3);
    const short* bab  = (const short*)(ws + OFF_BAB);   // l = 0

    // ---- GEMM1: K=320
    f32x4 acc[2];
    acc[0] = (f32x4){0.f, 0.f, 0.f, 0.f};
    acc[1] = (f32x4){0.f, 0.f, 0.f, 0.f};
    for (int s = 0; s < 10; s++) {
        int kb = s * 32 + quad * 8;
        float z[8];
        if (kb < 64) {
            const float* h0 = H0 + (size_t)nodeA * 64 + kb;
            const float* h1 = H1 + (size_t)nodeA * 64 + kb;
            #pragma unroll
            for (int e = 0; e < 8; e++) z[e] = (1.0f - u) * h0[e] + u * h1[e];
        } else if (kb < 192) {
            const float* cp = cond + (size_t)nodeA * 128 + (kb - 64);
            #pragma unroll
            for (int e = 0; e < 8; e++) z[e] = cp[e];
        } else if (kb < 256) {
            #pragma unroll
            for (int e = 0; e < 8; e++) {
                float c = (float)(kb - 192 + e);
                float fr = __expf(-9.2103403719761836f * c / 63.0f);
                z[e] = __sinf(t * fr);
            }
        } else {
            #pragma unroll
            for (int e = 0; e < 8; e++) {
                float c = (float)(kb - 256 + e);
                float fr = __expf(-9.2103403719761836f * c / 63.0f);
                z[e] = __cosf(t * fr);
            }
        }
        bf16x8 af;
        #pragma unroll
        for (int e = 0; e < 8; e += 2) {
            short2 p = f2bf2(z[e], z[e + 1]);
            af[e] = p.x; af[e + 1] = p.y;
        }
        #pragma unroll
        for (int i = 0; i < 2; i++) {
            int ct = 2 * w + i;
            bf16x8 bf = *(const bf16x8*)(bwi1 + (size_t)(16 * ct + lp) * 320 + kb);
            acc[i] = __builtin_amdgcn_mfma_f32_16x16x32_bf16(af, bf, acc[i], 0, 0, 0);
        }
    }
    #pragma unroll
    for (int i = 0; i < 2; i++) {
        int ch = 16 * (2 * w + i) + lp;
        float bb1 = bi1[ch];
        #pragma unroll
        for (int r = 0; r < 4; r++)
            u1[(quad * 4 + r) * 136 + ch] = f2bf(fmaxf(acc[i][r] + bb1, 0.0f));
    }
    __syncthreads();

    // ---- GEMM2: K=128
    acc[0] = (f32x4){0.f, 0.f, 0.f, 0.f};
    acc[1] = (f32x4){0.f, 0.f, 0.f, 0.f};
    #pragma unroll
    for (int s = 0; s < 4; s++) {
        int kb = s * 32 + quad * 8;
        bf16x8 af = *(const bf16x8*)(u1 + lp * 136 + kb);
        #pragma unroll
        for (int i = 0; i < 2; i++) {
            int ct = 2 * w + i;
            bf16x8 bf = *(const bf16x8*)(bwi2 + (size_t)(16 * ct + lp) * 128 + kb);
            acc[i] = __builtin_amdgcn_mfma_f32_16x16x32_bf16(af, bf, acc[i], 0, 0, 0);
        }
    }
    #pragma unroll
    for (int i = 0; i < 2; i++) {
        int ch = 16 * (2 * w + i) + lp;
        float bb2 = bi2[ch];
        #pragma unroll
        for (int r = 0; r < 4; r++)
            u2[(quad * 4 + r) * 136 + ch] = f2bf(fmaxf(acc[i][r] + bb2, 0.0f));
    }
    __syncthreads();

    // ---- GEMM3: K=128 -> h (no relu)
    acc[0] = (f32x4){0.f, 0.f, 0.f, 0.f};
    acc[1] = (f32x4){0.f, 0.f, 0.f, 0.f};
    #pragma unroll
    for (int s = 0; s < 4; s++) {
        int kb = s * 32 + quad * 8;
        bf16x8 af = *(const bf16x8*)(u2 + lp * 136 + kb);
        #pragma unroll
        for (int i = 0; i < 2; i++) {
            int ct = 2 * w + i;
            bf16x8 bf = *(const bf16x8*)(bwi3 + (size_t)(16 * ct + lp) * 128 + kb);
            acc[i] = __builtin_amdgcn_mfma_f32_16x16x32_bf16(af, bf, acc[i], 0, 0, 0);
        }
    }
    #pragma unroll
    for (int i = 0; i < 2; i++) {
        int ch = 16 * (2 * w + i) + lp;
        float bb3 = bi3[ch];
        #pragma unroll
        for (int r = 0; r < 4; r++) {
            int row = quad * 4 + r;
            float h = acc[i][r] + bb3;
            ws[OFF_H + (size_t)(rowbase + row) * 128 + ch] = h;
            u1[row * 136 + ch] = f2bf(h);
        }
    }
    __syncthreads();

    // ---- GEMM4: pa/pb layer 0, N=256 (ct4 = 4w..4w+3)
    f32x4 acc4[4];
    #pragma unroll
    for (int i = 0; i < 4; i++) acc4[i] = (f32x4){0.f, 0.f, 0.f, 0.f};
    #pragma unroll
    for (int s = 0; s < 4; s++) {
        int kb = s * 32 + quad * 8;
        bf16x8 af = *(const bf16x8*)(u1 + lp * 136 + kb);
        #pragma unroll
        for (int i = 0; i < 4; i++) {
            int ct4 = 4 * w + i;
            bf16x8 bf = *(const bf16x8*)(bab + (size_t)(16 * ct4 + lp) * 128 + kb);
            acc4[i] = __builtin_amdgcn_mfma_f32_16x16x32_bf16(af, bf, acc4[i], 0, 0, 0);
        }
    }
    short* pbh = (short*)(ws + OFF_PBH);
    #pragma unroll
    for (int i = 0; i < 4; i++) {
        int ct4 = 4 * w + i;
        #pragma unroll
        for (int r = 0; r < 4; r++) {
            int node = rowbase + quad * 4 + r;
            if (ct4 < 8) {
                int ch = 16 * ct4 + lp;
                ws[OFF_PA + (size_t)node * 128 + ch] = acc4[i][r] + be1[ch];
            } else {
                int ch = 16 * (ct4 - 8) + lp;
                pbh[(size_t)node * 128 + ch] = f2bf(acc4[i][r]);
            }
        }
    }
}

// -------- K3c: edge kernel — R12 structure, g-loop NOT unrolled.
// Code-footprint experiment: fully-unrolled 4-target body is ~15-20 KB of
// straight-line code (~sL1I capacity); rolled g-loop shares one ~4 KB body.
#define KG 4
#define SMC_BS    0        // short[2048][8] swizzled = 32768
#define SMC_AGG   32768    // float[6*128] = 3072
#define SMC_PA    35840    // float[KG*128] = 2048
#define SMC_ET    37888    // float[2*128] = 1024
#define SMC_WC    38912    // float[128] = 512
#define SMC_COEF  39424    // float[96] = 384
#define SMC_XT    39808    // float[12] = 48
#define SMC_CI    39856    // int[4] = 16  -> total 39872
__global__ void __launch_bounds__(384)
k3c_edge(const float* __restrict__ We1, const float* __restrict__ Wx,
         const float* __restrict__ be2, const int* __restrict__ chain,
         int l, float* __restrict__ ws) {
    __shared__ __align__(16) char smem[39872];
    short* bS    = (short*)(smem + SMC_BS);
    float* aggP  = (float*)(smem + SMC_AGG);
    float* paS   = (float*)(smem + SMC_PA);
    float* etS   = (float*)(smem + SMC_ET);
    float* wcS   = (float*)(smem + SMC_WC);
    float* coefS = (float*)(smem + SMC_COEF);
    float* xT    = (float*)(smem + SMC_XT);
    int*   ciS   = (int*)  (smem + SMC_CI);

    int tid = threadIdx.x;
    int i0 = blockIdx.x * KG;
    int colbase = (i0 / 96) * 96;
    const float* Xc = ws + OFF_X;

    // ---- stage: swizzled B + per-target pa + et + wc
    {
        const short* bpe = (const short*)(ws + OFF_BPE) + (size_t)l * 128 * 128;
        for (int idx = tid; idx < 2048; idx += 384) {
            int t = idx >> 8, s = (idx >> 6) & 3, ln = idx & 63;
            int lq = ln >> 4, lpp = ln & 15;
            *(bf16x8*)(bS + idx * 8) =
                *(const bf16x8*)(bpe + (size_t)(16 * t + lpp) * 128 + s * 32 + lq * 8);
        }
        if (tid < 128) {
            #pragma unroll
            for (int g = 0; g < KG; g++)
                paS[g * 128 + tid] = ws[OFF_PA + (size_t)(i0 + g) * 128 + tid];
            etS[tid]       = ws[OFF_ET + l * 256 + tid];
            etS[128 + tid] = ws[OFF_ET + l * 256 + 128 + tid];
            wcS[tid]       = We1[(l * 289 + 256) * 128 + tid];
        }
        if (tid < KG * 3) xT[tid] = Xc[(size_t)(i0 + tid / 3) * 3 + tid % 3];
        if (tid < KG) ciS[tid] = chain[i0 + tid];
    }

    int w = tid >> 6, lane = tid & 63;
    int quad = lane >> 4, lp = lane & 15;
    int jA = 16 * w + lp;                       // lane's fixed source row
    const short* pbrow = (const short*)(ws + OFF_PBH) + (size_t)(colbase + jA) * 128;
    bf16x8 pbv[4];
    #pragma unroll
    for (int s = 0; s < 4; s++) pbv[s] = *(const bf16x8*)(pbrow + s * 32 + quad * 8);
    float xr0 = Xc[(size_t)(colbase + jA) * 3 + 0];
    float xr1 = Xc[(size_t)(colbase + jA) * 3 + 1];
    float xr2 = Xc[(size_t)(colbase + jA) * 3 + 2];
    int cj = chain[colbase + jA];
    float be2r[8], wxr[8];
    #pragma unroll
    for (int t = 0; t < 8; t++) {
        int ch = 16 * t + lp;
        be2r[t] = be2[l * 128 + ch];
        wxr[t]  = Wx[l * 128 + ch];
    }
    // epilogue x hoists (waves 0..2 only use them)
    float ex0 = 0.f, ex1 = 0.f;
    if (w < 3) {
        ex0 = Xc[(size_t)(colbase + lane) * 3 + w];
        if (lane < 32) ex1 = Xc[(size_t)(colbase + lane + 64) * 3 + w];
    }
    __syncthreads();

    #pragma clang loop unroll(disable)
    for (int g = 0; g < KG; g++) {
        float rx = xT[g * 3 + 0] - xr0;
        float ry = xT[g * 3 + 1] - xr1;
        float rz = xT[g * 3 + 2] - xr2;
        float d2j = rx * rx + ry * ry + rz * rz;
        const float* etP = etS + ((cj != ciS[g]) ? 128 : 0);
        const float* paP = paS + g * 128;

        f32x4 acc[8];
        #pragma unroll
        for (int t = 0; t < 8; t++) acc[t] = (f32x4){0.f, 0.f, 0.f, 0.f};

        #pragma unroll
        for (int s = 0; s < 4; s++) {
            int kb = s * 32 + quad * 8;
            float z[8];
            #pragma unroll
            for (int e = 0; e < 8; e++)
                z[e] = silu(paP[kb + e] + etP[kb + e] + bf2f(pbv[s][e]) + d2j * wcS[kb + e]);
            bf16x8 af;
            #pragma unroll
            for (int e = 0; e < 8; e += 2) {
                short2 p = f2bf2(z[e], z[e + 1]);
                af[e] = p.x; af[e + 1] = p.y;
            }
            #pragma unroll
            for (int t = 0; t < 8; t++) {
                bf16x8 bf = *(const bf16x8*)(bS + ((t * 4 + s) * 64 + lane) * 8);
                acc[t] = __builtin_amdgcn_mfma_f32_16x16x32_bf16(af, bf, acc[t], 0, 0, 0);
            }
        }

        // epilogue: m2[row=16w+quad*4+r][chan=16t+lp]
        float cp[4] = {0.f, 0.f, 0.f, 0.f};
        #pragma unroll
        for (int t = 0; t < 8; t++) {
            float ag = 0.f;
            #pragma unroll
            for (int r = 0; r < 4; r++) {
                float m2 = silu(acc[t][r] + be2r[t]);
                ag += m2;
                cp[r] += m2 * wxr[t];
            }
            ag += __shfl_xor(ag, 16);
            ag += __shfl_xor(ag, 32);
            if (lane < 16) aggP[w * 128 + 16 * t + lp] = ag;
        }
        #pragma unroll
        for (int r = 0; r < 4; r++) {
            float v = cp[r];
            v += __shfl_xor(v, 1);
            v += __shfl_xor(v, 2);
            v += __shfl_xor(v, 4);
            v += __shfl_xor(v, 8);
            if (lp == 0) coefS[16 * w + quad * 4 + r] = v;
        }
        __syncthreads();

        if (tid < 128) {
            float s = 0.f;
            #pragma unroll
            for (int q = 0; q < 6; q++) s += aggP[q * 128 + tid];
            ws[OFF_AGG + (size_t)(i0 + g) * 128 + tid] = s;
        }
        if (w < 3) {
            float v = (xT[g * 3 + w] - ex0) * coefS[lane];
            if (lane < 32) v += (xT[g * 3 + w] - ex1) * coefS[lane + 64];
            #pragma unroll
            for (int o = 32; o > 0; o >>= 1) v += __shfl_down(v, o);
            if (lane == 0) ws[OFF_DX + (size_t)(i0 + g) * 3 + w] = v;
        }
        __syncthreads();
    }
}

// ----- K4s: node update row-split — grid (32, 6), 256 thr, 16 nodes/WG
// + pa/pb(l+1) (l<2) or loss (l==2, with 192-WG election final write-out)
__global__ void __launch_bounds__(256)
k4s_node_post(const float* __restrict__ bh1, const float* __restrict__ bh2,
              const float* __restrict__ be1, const float* __restrict__ bout,
              const float* __restrict__ H0, const float* __restrict__ X0,
              const float* __restrict__ H1, const float* __restrict__ X1,
              const int* __restrict__ gmask, const int* __restrict__ shiftp,
              int l, float* __restrict__ ws, float* __restrict__ out) {
    __shared__ short uS[16 * 136];
    __shared__ short hS[16 * 136];
    __shared__ float redE[4], redN[4];
    __shared__ float sxp, sxn, scnt;
    int rowbase = blockIdx.x * 96 + blockIdx.y * 16;
    int tid = threadIdx.x;
    int w = tid >> 6, lane = tid & 63;
    int quad = lane >> 4, lp = lane & 15;
    int nodeA = rowbase + lp;
    const short* b1 = (const short*)(ws + OFF_BH1) + (size_t)l * 128 * 256;
    const short* b2 = (const short*)(ws + OFF_BH2) + (size_t)l * 128 * 128;

    if (tid == 0) { sxp = 0.f; sxn = 0.f; scnt = 0.f; }
    if (tid < 48) {
        int node = rowbase + tid / 3, d = tid % 3;
        ws[OFF_X + (size_t)node * 3 + d] += ws[OFF_DX + (size_t)node * 3 + d];
    }

    // ---- GEMM1: [h|agg] K=256 -> u (silu); ct = 2w+i
    f32x4 acc[2];
    acc[0] = (f32x4){0.f, 0.f, 0.f, 0.f};
    acc[1] = (f32x4){0.f, 0.f, 0.f, 0.f};
    #pragma unroll
    for (int s = 0; s < 8; s++) {
        int kb = s * 32 + quad * 8;
        const float* src = (kb < 128) ? (ws + OFF_H + (size_t)nodeA * 128 + kb)
                                      : (ws + OFF_AGG + (size_t)nodeA * 128 + (kb - 128));
        bf16x8 af;
        #pragma unroll
        for (int e = 0; e < 8; e += 2) {
            short2 p = f2bf2(src[e], src[e + 1]);
            af[e] = p.x; af[e + 1] = p.y;
        }
        #pragma unroll
        for (int i = 0; i < 2; i++) {
            int ct = 2 * w + i;
            bf16x8 bf = *(const bf16x8*)(b1 + (size_t)(16 * ct + lp) * 256 + kb);
            acc[i] = __builtin_amdgcn_mfma_f32_16x16x32_bf16(af, bf, acc[i], 0, 0, 0);
        }
    }
    #pragma unroll
    for (int i = 0; i < 2; i++) {
        int ch = 16 * (2 * w + i) + lp;
        float bb1 = bh1[l * 128 + ch];
        #pragma unroll
        for (int r = 0; r < 4; r++)
            uS[(quad * 4 + r) * 136 + ch] = f2bf(silu(acc[i][r] + bb1));
    }
    __syncthreads();

    // ---- GEMM2: u @ Wh2 -> h += ; hS = bf16(h)
    acc[0] = (f32x4){0.f, 0.f, 0.f, 0.f};
    acc[1] = (f32x4){0.f, 0.f, 0.f, 0.f};
    #pragma unroll
    for (int s = 0; s < 4; s++) {
        int kb = s * 32 + quad * 8;
        bf16x8 af = *(const bf16x8*)(uS + lp * 136 + kb);
        #pragma unroll
        for (int i = 0; i < 2; i++) {
            int ct = 2 * w + i;
            bf16x8 bf = *(const bf16x8*)(b2 + (size_t)(16 * ct + lp) * 128 + kb);
            acc[i] = __builtin_amdgcn_mfma_f32_16x16x32_bf16(af, bf, acc[i], 0, 0, 0);
        }
    }
    #pragma unroll
    for (int i = 0; i < 2; i++) {
        int ch = 16 * (2 * w + i) + lp;
        float bb2 = bh2[l * 128 + ch];
        #pragma unroll
        for (int r = 0; r < 4; r++) {
            int row = quad * 4 + r;
            size_t off = OFF_H + (size_t)(rowbase + row) * 128 + ch;
            float h = ws[off] + acc[i][r] + bb2;
            ws[off] = h;
            hS[row * 136 + ch] = f2bf(h);
        }
    }
    __syncthreads();

    if (l < 2) {
        // ---- GEMM3: pa/pb for layer l+1, N=256 (ct4 = 4w+i)
        const short* bab = (const short*)(ws + OFF_BAB) + (size_t)(l + 1) * 256 * 128;
        f32x4 acc4[4];
        #pragma unroll
        for (int i = 0; i < 4; i++) acc4[i] = (f32x4){0.f, 0.f, 0.f, 0.f};
        #pragma unroll
        for (int s = 0; s < 4; s++) {
            int kb = s * 32 + quad * 8;
            bf16x8 af = *(const bf16x8*)(hS + lp * 136 + kb);
            #pragma unroll
            for (int i = 0; i < 4; i++) {
                int ct4 = 4 * w + i;
                bf16x8 bf = *(const bf16x8*)(bab + (size_t)(16 * ct4 + lp) * 128 + kb);
                acc4[i] = __builtin_amdgcn_mfma_f32_16x16x32_bf16(af, bf, acc4[i], 0, 0, 0);
            }
        }
        short* pbh = (short*)(ws + OFF_PBH);
        #pragma unroll
        for (int i = 0; i < 4; i++) {
            int ct4 = 4 * w + i;
            #pragma unroll
            for (int r = 0; r < 4; r++) {
                int node = rowbase + quad * 4 + r;
                if (ct4 < 8) {
                    int ch = 16 * ct4 + lp;
                    ws[OFF_PA + (size_t)node * 128 + ch] = acc4[i][r] + be1[(l + 1) * 128 + ch];
                } else {
                    int ch = 16 * (ct4 - 8) + lp;
                    pbh[(size_t)node * 128 + ch] = f2bf(acc4[i][r]);
                }
            }
        }
    } else {
        // ---- GEMM3: v = h @ Wout^T (N=64, ct=w) + loss reduction + final out
        const short* bwo = (const short*)(ws + OFF_BWO);
        f32x4 accv = (f32x4){0.f, 0.f, 0.f, 0.f};
        #pragma unroll
        for (int s = 0; s < 4; s++) {
            int kb = s * 32 + quad * 8;
            bf16x8 af = *(const bf16x8*)(hS + lp * 136 + kb);
            bf16x8 bf = *(const bf16x8*)(bwo + (size_t)(16 * w + lp) * 128 + kb);
            accv = __builtin_amdgcn_mfma_f32_16x16x32_bf16(af, bf, accv, 0, 0, 0);
        }
        int s = shiftp[0] % NN; if (s < 0) s += NN;
        int col = 16 * w + lp;
        float bo = bout[col];
        float ep = 0.f, en = 0.f;
        #pragma unroll
        for (int r = 0; r < 4; r++) {
            int row = rowbase + quad * 4 + r;
            if (gmask[row] != 0) {
                int ip = row + s; if (ip >= NN) ip -= NN;
                float v  = accv[r] + bo;
                float tp = H1[(size_t)row * 64 + col] - H0[(size_t)row * 64 + col];
                float tn = H1[(size_t)ip * 64 + col]  - H0[(size_t)ip * 64 + col];
                float dp = v - tp, dn = v - tn;
                ep += dp * dp;
                en += dn * dn;
            }
        }
        #pragma unroll
        for (int o = 1; o < 64; o <<= 1) {
            ep += __shfl_xor(ep, o);
            en += __shfl_xor(en, o);
        }
        if (lane == 0) { redE[w] = ep; redN[w] = en; }

        if (tid < 16) {
            int node = rowbase + tid;
            if (gmask[node] != 0) {
                int ip = node + s; if (ip >= NN) ip -= NN;
                float xp = 0.f, xn = 0.f;
                #pragma unroll
                for (int d = 0; d < 3; d++) {
                    float xv  = ws[OFF_X + (size_t)node * 3 + d];
                    float tpx = X1[(size_t)node * 3 + d] - X0[(size_t)node * 3 + d];
                    float tnx = X1[(size_t)ip * 3 + d]   - X0[(size_t)ip * 3 + d];
                    xp += (xv - tpx) * (xv - tpx);
                    xn += (xv - tnx) * (xv - tnx);
                }
                atomicAdd(&sxp, xp);
                atomicAdd(&sxn, xn);
                atomicAdd(&scnt, 1.0f);
            }
        }
        __syncthreads();
        if (tid == 0) {
            float eT = redE[0] + redE[1] + redE[2] + redE[3];
            float nT = redN[0] + redN[1] + redN[2] + redN[3];
            float* acc0 = ws + OFF_ACC;
            atomicAdd(acc0 + 0, eT);
            atomicAdd(acc0 + 2, nT);
            atomicAdd(acc0 + 1, sxp);
            atomicAdd(acc0 + 3, sxn);
            atomicAdd(acc0 + 4, scnt);
            // ---- final election among the 192 l==2 WGs: write out
            __threadfence();
            unsigned o2 = atomicAdd((unsigned*)(ws + OFF_CNT) + 96, 1u);
            if (o2 == 191u) {
                __threadfence();
                float a0 = atomicAdd(acc0 + 0, 0.0f);
                float a1 = atomicAdd(acc0 + 1, 0.0f);
                float a2 = atomicAdd(acc0 + 2, 0.0f);
                float a3 = atomicAdd(acc0 + 3, 0.0f);
                float a4 = atomicAdd(acc0 + 4, 0.0f);
                float msum = a4 + 1e-8f;
                float lhp = a0 / msum, lxp = a1 / msum;
                float lhn = a2 / msum, lxn = a3 / msum;
                out[0] = lhp - 0.05f * lhn;
                out[1] = lxp - 0.05f * lxn;
                out[2] = lhp;
                out[3] = lxp;
                out[4] = lhn;
                out[5] = lxn;
            }
        }
    }
}

extern "C" void kernel_launch(void* const* d_in, const int* in_sizes, int n_in,
                              void* d_out, int out_size, void* d_ws, size_t ws_size,
                              hipStream_t stream) {
    (void)in_sizes; (void)n_in; (void)out_size; (void)ws_size;
    const float* H0   = (const float*)d_in[0];
    const float* X0   = (const float*)d_in[1];
    const float* H1   = (const float*)d_in[2];
    const float* X1   = (const float*)d_in[3];
    const float* cond = (const float*)d_in[4];
    const float* tg   = (const float*)d_in[5];
    const float* Wi1  = (const float*)d_in[6];
    const float* bi1  = (const float*)d_in[7];
    const float* Wi2  = (const float*)d_in[8];
    const float* bi2  = (const float*)d_in[9];
    const float* Wi3  = (const float*)d_in[10];
    const float* bi3  = (const float*)d_in[11];
    const float* etab = (const float*)d_in[12];
    const float* We1  = (const float*)d_in[13];
    const float* be1  = (const float*)d_in[14];
    const float* We2  = (const float*)d_in[15];
    const float* be2  = (const float*)d_in[16];
    const float* Wx   = (const float*)d_in[17];
    const float* Wh1  = (const float*)d_in[18];
    const float* bh1  = (const float*)d_in[19];
    const float* Wh2  = (const float*)d_in[20];
    const float* bh2  = (const float*)d_in[21];
    const float* Wout = (const float*)d_in[22];
    const float* bout = (const float*)d_in[23];
    const int* chain   = (const int*)d_in[25];
    const int* gmask   = (const int*)d_in[26];
    const int* lengths = (const int*)d_in[27];
    const int* shiftp  = (const int*)d_in[28];
    float* ws  = (float*)d_ws;
    float* out = (float*)d_out;

    k0_all<<<1473, 256, 0, stream>>>(etab, We1, lengths, We2, Wh1, Wh2,
                                     Wout, Wi1, Wi2, Wi3, ws);
    k1s_node_init<<<dim3(NBATCH, 6), 256, 0, stream>>>(H0, X0, H1, X1, cond, tg,
                                                       bi1, bi2, bi3, be1, gmask, ws);
    for (int l = 0; l < 3; l++) {
        k3c_edge<<<NN / KG, 384, 0, stream>>>(We1, Wx, be2, chain, l, ws);
        k4s_node_post<<<dim3(NBATCH, 6), 256, 0, stream>>>(bh1, bh2, be1, bout,
                                                           H0, X0, H1, X1, gmask, shiftp,
                                                           l, ws, out);
    }
}

// Round 15
// 376.651 us; speedup vs baseline: 1.0956x; 1.0412x over previous
//
#include <hip/hip_runtime.h>
#include <hip/hip_bf16.h>
#include <math.h>

// Problem constants
#define NBATCH 32
#define LSEQ   96
#define NN     3072
#define HID    128
#define LAT    64
#define EEMB   32

// Workspace layout (float offsets). Total ~6.35 MB.
#define OFF_H      0                          // N x 128 fp32
#define OFF_X      (OFF_H   + NN*HID)         // N x 3
#define OFF_PA     (OFF_X   + NN*3)           // N x 128 fp32 (pa + be1)
#define OFF_AGG    (OFF_PA  + NN*HID)         // N x 128
#define OFF_DX     (OFF_AGG + NN*HID)         // N x 3
#define OFF_ET     (OFF_DX  + NN*3)           // 3*2*128 fp32
#define OFF_ACC    (OFF_ET  + 768)            // 8
#define OFF_NBID   (OFF_ACC + 8)              // N int
#define OFF_CUM    (OFF_NBID + NN)            // 40 int
#define OFF_PBH    (OFF_CUM + 40)             // N x 128 bf16 (as 196608 floats)
#define OFF_BPE    (OFF_PBH + NN*HID/2)       // We2^T  bf16: 3*128*128 -> 24576 floats
#define OFF_BAB    (OFF_BPE + 24576)          // We1[0:256]^T bf16: 3*256*128 -> 49152
#define OFF_BH1    (OFF_BAB + 49152)          // Wh1^T bf16: 3*128*256 -> 49152
#define OFF_BH2    (OFF_BH1 + 49152)          // Wh2^T bf16: 3*128*128 -> 24576
#define OFF_BWO    (OFF_BH2 + 24576)          // Wout^T bf16: 64*128 -> 4096 floats
#define OFF_BWI1   (OFF_BWO + 4096)           // Wi1^T bf16: 128x320 -> 20480 floats
#define OFF_BWI2   (OFF_BWI1 + 20480)         // Wi2^T bf16: 128x128 -> 8192 floats
#define OFF_BWI3   (OFF_BWI2 + 8192)          // Wi3^T bf16: 128x128 -> 8192 floats
#define OFF_CNT    (OFF_BWI3 + 8192)          // 128 uint: [96] = final-election counter

typedef short bf16x8 __attribute__((ext_vector_type(8)));
typedef float f32x4  __attribute__((ext_vector_type(4)));

__device__ __forceinline__ short f2bf(float f) {
    unsigned u = __builtin_bit_cast(unsigned, f);
    unsigned r = (u + 0x7FFFu + ((u >> 16) & 1u)) >> 16;
    return (short)r;
}
__device__ __forceinline__ short2 f2bf2(float a, float b) {
    __hip_bfloat162 h = __float22bfloat162_rn(make_float2(a, b));
    short2 r;
    __builtin_memcpy(&r, &h, sizeof(r));
    return r;
}
__device__ __forceinline__ float bf2f(short s) {
    unsigned u = ((unsigned)(unsigned short)s) << 16;
    return __builtin_bit_cast(float, u);
}
__device__ __forceinline__ float silu(float z) {
    return z * __builtin_amdgcn_rcpf(1.0f + __expf(-z));
}

// --------------------- K0: prep + weight transposes (merged)
__global__ void k0_all(const float* __restrict__ edge_table, const float* __restrict__ We1,
                       const int* __restrict__ lengths, const float* __restrict__ We2,
                       const float* __restrict__ Wh1, const float* __restrict__ Wh2,
                       const float* __restrict__ Wout, const float* __restrict__ Wi1,
                       const float* __restrict__ Wi2, const float* __restrict__ Wi3,
                       float* __restrict__ ws) {
    int tid = threadIdx.x;
    if (blockIdx.x == 1472) {
        int* cum = (int*)(ws + OFF_CUM);
        int* nb  = (int*)(ws + OFF_NBID);
        float* et = ws + OFF_ET;
        if (tid == 0) {
            int s = 0;
            for (int b = 0; b < NBATCH; b++) { cum[b] = s; s += lengths[b]; }
            cum[NBATCH] = s;
        }
        if (tid < 8) ws[OFF_ACC + tid] = 0.0f;
        if (tid < 128) ((unsigned*)(ws + OFF_CNT))[tid] = 0u;
        __syncthreads();
        for (int i = tid; i < NN; i += blockDim.x) {
            int b = NBATCH - 1;
            for (int q = 0; q < NBATCH; q++) { if (i < cum[q + 1]) { b = q; break; } }
            nb[i] = b;
        }
        for (int idx = tid; idx < 3 * 2 * HID; idx += blockDim.x) {
            int c = idx & 127;
            int t = (idx >> 7) & 1;
            int l = idx >> 8;
            const float* w = We1 + (l * 289 + 257) * HID + c;
            const float* e = edge_table + t * EEMB;
            float s = 0.f;
            for (int k = 0; k < EEMB; k++) s += e[k] * w[k * HID];
            et[idx] = s;
        }
        return;
    }
    int idx = blockIdx.x * 256 + tid;   // 0 .. 376831
    short* bpe  = (short*)(ws + OFF_BPE);
    short* bab  = (short*)(ws + OFF_BAB);
    short* bh1  = (short*)(ws + OFF_BH1);
    short* bh2  = (short*)(ws + OFF_BH2);
    short* bwo  = (short*)(ws + OFF_BWO);
    short* bwi1 = (short*)(ws + OFF_BWI1);
    short* bwi2 = (short*)(ws + OFF_BWI2);
    short* bwi3 = (short*)(ws + OFF_BWI3);
    if (idx < 49152) {
        int k = idx & 127, n = (idx >> 7) & 127, l = idx >> 14;
        bpe[idx] = f2bf(We2[(l * 128 + k) * 128 + n]);
    } else if (idx < 147456) {
        int q = idx - 49152;
        int k = q & 127, n = (q >> 7) & 255, l = q >> 15;
        float v = (n < 128) ? We1[(l * 289 + k) * 128 + n]
                            : We1[(l * 289 + 128 + k) * 128 + (n - 128)];
        bab[q] = f2bf(v);
    } else if (idx < 245760) {
        int q = idx - 147456;
        int k = q & 255, n = (q >> 8) & 127, l = q >> 15;
        bh1[q] = f2bf(Wh1[(l * 256 + k) * 128 + n]);
    } else if (idx < 294912) {
        int q = idx - 245760;
        int k = q & 127, n = (q >> 7) & 127, l = q >> 14;
        bh2[q] = f2bf(Wh2[(l * 128 + k) * 128 + n]);
    } else if (idx < 303104) {
        int q = idx - 294912;
        int k = q & 127, n = q >> 7;          // n < 64
        bwo[q] = f2bf(Wout[k * 64 + n]);
    } else if (idx < 344064) {
        int q = idx - 303104;                  // [n<128][k<320]
        int n = q / 320, k = q - n * 320;
        bwi1[q] = f2bf(Wi1[k * 128 + n]);
    } else if (idx < 360448) {
        int q = idx - 344064;
        int k = q & 127, n = q >> 7;
        bwi2[q] = f2bf(Wi2[k * 128 + n]);
    } else if (idx < 376832) {
        int q = idx - 360448;
        int k = q & 127, n = q >> 7;
        bwi3[q] = f2bf(Wi3[k * 128 + n]);
    }
}

// ------------- K1s: init MLP row-split — grid (32, 6), 256 thr, 16 nodes/WG
__global__ void __launch_bounds__(256)
k1s_node_init(const float* __restrict__ H0, const float* __restrict__ X0,
              const float* __restrict__ H1, const float* __restrict__ X1,
              const float* __restrict__ cond, const float* __restrict__ tg,
              const float* __restrict__ bi1, const float* __restrict__ bi2,
              const float* __restrict__ bi3, const float* __restrict__ be1,
              const int* __restrict__ gmask, float* __restrict__ ws) {
    __shared__ short u1[16 * 136];
    __shared__ short u2[16 * 136];
    int rowbase = blockIdx.x * 96 + blockIdx.y * 16;
    int tid = threadIdx.x;
    int w = tid >> 6, lane = tid & 63;
    int quad = lane >> 4, lp = lane & 15;
    int nodeA = rowbase + lp;
    const int* nb = (const int*)(ws + OFF_NBID);
    float t = tg[nb[nodeA]];
    float u = (gmask[nodeA] != 0) ? t : 1.0f;

    if (tid < 48) {
        int node = rowbase + tid / 3, d = tid % 3;
        float tn = tg[nb[node]];
        float un = (gmask[node] != 0) ? tn : 1.0f;
        ws[OFF_X + (size_t)node * 3 + d] =
            (1.0f - un) * X0[(size_t)node * 3 + d] + un * X1[(size_t)node * 3 + d];
    }

    const short* bwi1 = (const short*)(ws + OFF_BWI1);
    const short* bwi2 = (const short*)(ws + OFF_BWI2);
    const short* bwi3 = (const short*)(ws + OFF_BWI3);
    const short* bab  = (const short*)(ws + OFF_BAB);   // l = 0

    // ---- GEMM1: K=320
    f32x4 acc[2];
    acc[0] = (f32x4){0.f, 0.f, 0.f, 0.f};
    acc[1] = (f32x4){0.f, 0.f, 0.f, 0.f};
    for (int s = 0; s < 10; s++) {
        int kb = s * 32 + quad * 8;
        float z[8];
        if (kb < 64) {
            const float* h0 = H0 + (size_t)nodeA * 64 + kb;
            const float* h1 = H1 + (size_t)nodeA * 64 + kb;
            #pragma unroll
            for (int e = 0; e < 8; e++) z[e] = (1.0f - u) * h0[e] + u * h1[e];
        } else if (kb < 192) {
            const float* cp = cond + (size_t)nodeA * 128 + (kb - 64);
            #pragma unroll
            for (int e = 0; e < 8; e++) z[e] = cp[e];
        } else if (kb < 256) {
            #pragma unroll
            for (int e = 0; e < 8; e++) {
                float c = (float)(kb - 192 + e);
                float fr = __expf(-9.2103403719761836f * c / 63.0f);
                z[e] = __sinf(t * fr);
            }
        } else {
            #pragma unroll
            for (int e = 0; e < 8; e++) {
                float c = (float)(kb - 256 + e);
                float fr = __expf(-9.2103403719761836f * c / 63.0f);
                z[e] = __cosf(t * fr);
            }
        }
        bf16x8 af;
        #pragma unroll
        for (int e = 0; e < 8; e += 2) {
            short2 p = f2bf2(z[e], z[e + 1]);
            af[e] = p.x; af[e + 1] = p.y;
        }
        #pragma unroll
        for (int i = 0; i < 2; i++) {
            int ct = 2 * w + i;
            bf16x8 bf = *(const bf16x8*)(bwi1 + (size_t)(16 * ct + lp) * 320 + kb);
            acc[i] = __builtin_amdgcn_mfma_f32_16x16x32_bf16(af, bf, acc[i], 0, 0, 0);
        }
    }
    #pragma unroll
    for (int i = 0; i < 2; i++) {
        int ch = 16 * (2 * w + i) + lp;
        float bb1 = bi1[ch];
        #pragma unroll
        for (int r = 0; r < 4; r++)
            u1[(quad * 4 + r) * 136 + ch] = f2bf(fmaxf(acc[i][r] + bb1, 0.0f));
    }
    __syncthreads();

    // ---- GEMM2: K=128
    acc[0] = (f32x4){0.f, 0.f, 0.f, 0.f};
    acc[1] = (f32x4){0.f, 0.f, 0.f, 0.f};
    #pragma unroll
    for (int s = 0; s < 4; s++) {
        int kb = s * 32 + quad * 8;
        bf16x8 af = *(const bf16x8*)(u1 + lp * 136 + kb);
        #pragma unroll
        for (int i = 0; i < 2; i++) {
            int ct = 2 * w + i;
            bf16x8 bf = *(const bf16x8*)(bwi2 + (size_t)(16 * ct + lp) * 128 + kb);
            acc[i] = __builtin_amdgcn_mfma_f32_16x16x32_bf16(af, bf, acc[i], 0, 0, 0);
        }
    }
    #pragma unroll
    for (int i = 0; i < 2; i++) {
        int ch = 16 * (2 * w + i) + lp;
        float bb2 = bi2[ch];
        #pragma unroll
        for (int r = 0; r < 4; r++)
            u2[(quad * 4 + r) * 136 + ch] = f2bf(fmaxf(acc[i][r] + bb2, 0.0f));
    }
    __syncthreads();

    // ---- GEMM3: K=128 -> h (no relu)
    acc[0] = (f32x4){0.f, 0.f, 0.f, 0.f};
    acc[1] = (f32x4){0.f, 0.f, 0.f, 0.f};
    #pragma unroll
    for (int s = 0; s < 4; s++) {
        int kb = s * 32 + quad * 8;
        bf16x8 af = *(const bf16x8*)(u2 + lp * 136 + kb);
        #pragma unroll
        for (int i = 0; i < 2; i++) {
            int ct = 2 * w + i;
            bf16x8 bf = *(const bf16x8*)(bwi3 + (size_t)(16 * ct + lp) * 128 + kb);
            acc[i] = __builtin_amdgcn_mfma_f32_16x16x32_bf16(af, bf, acc[i], 0, 0, 0);
        }
    }
    #pragma unroll
    for (int i = 0; i < 2; i++) {
        int ch = 16 * (2 * w + i) + lp;
        float bb3 = bi3[ch];
        #pragma unroll
        for (int r = 0; r < 4; r++) {
            int row = quad * 4 + r;
            float h = acc[i][r] + bb3;
            ws[OFF_H + (size_t)(rowbase + row) * 128 + ch] = h;
            u1[row * 136 + ch] = f2bf(h);
        }
    }
    __syncthreads();

    // ---- GEMM4: pa/pb layer 0, N=256 (ct4 = 4w..4w+3)
    f32x4 acc4[4];
    #pragma unroll
    for (int i = 0; i < 4; i++) acc4[i] = (f32x4){0.f, 0.f, 0.f, 0.f};
    #pragma unroll
    for (int s = 0; s < 4; s++) {
        int kb = s * 32 + quad * 8;
        bf16x8 af = *(const bf16x8*)(u1 + lp * 136 + kb);
        #pragma unroll
        for (int i = 0; i < 4; i++) {
            int ct4 = 4 * w + i;
            bf16x8 bf = *(const bf16x8*)(bab + (size_t)(16 * ct4 + lp) * 128 + kb);
            acc4[i] = __builtin_amdgcn_mfma_f32_16x16x32_bf16(af, bf, acc4[i], 0, 0, 0);
        }
    }
    short* pbh = (short*)(ws + OFF_PBH);
    #pragma unroll
    for (int i = 0; i < 4; i++) {
        int ct4 = 4 * w + i;
        #pragma unroll
        for (int r = 0; r < 4; r++) {
            int node = rowbase + quad * 4 + r;
            if (ct4 < 8) {
                int ch = 16 * ct4 + lp;
                ws[OFF_PA + (size_t)node * 128 + ch] = acc4[i][r] + be1[ch];
            } else {
                int ch = 16 * (ct4 - 8) + lp;
                pbh[(size_t)node * 128 + ch] = f2bf(acc4[i][r]);
            }
        }
    }
}

// -------- K3v: edge kernel — R12 structure + VECTORIZED LDS A-build reads.
// pe0/pe1 = pa+et fused at stage time; peB and wcS read as float4 (b128
// broadcast). Cuts A-build LDS issue ~4x — the only untested dimension.
#define KG 4
#define SMC_BS    0        // short[2048][8] swizzled = 32768
#define SMC_AGG   32768    // float[6*128] = 3072
#define SMC_PE0   35840    // float[KG*128] = 2048
#define SMC_PE1   37888    // float[KG*128] = 2048
#define SMC_WC    39936    // float[128] = 512
#define SMC_COEF  40448    // float[96] = 384
#define SMC_XT    40832    // float[12] = 48
#define SMC_CI    40880    // int[4] = 16  -> total 40896
__global__ void __launch_bounds__(384)
k3v_edge(const float* __restrict__ We1, const float* __restrict__ Wx,
         const float* __restrict__ be2, const int* __restrict__ chain,
         int l, float* __restrict__ ws) {
    __shared__ __align__(16) char smem[40896];
    short* bS    = (short*)(smem + SMC_BS);
    float* aggP  = (float*)(smem + SMC_AGG);
    float* pe0S  = (float*)(smem + SMC_PE0);
    float* pe1S  = (float*)(smem + SMC_PE1);
    float* wcS   = (float*)(smem + SMC_WC);
    float* coefS = (float*)(smem + SMC_COEF);
    float* xT    = (float*)(smem + SMC_XT);
    int*   ciS   = (int*)  (smem + SMC_CI);

    int tid = threadIdx.x;
    int i0 = blockIdx.x * KG;
    int colbase = (i0 / 96) * 96;
    const float* Xc = ws + OFF_X;

    // ---- stage: swizzled B + fused pe0/pe1 + wc
    {
        const short* bpe = (const short*)(ws + OFF_BPE) + (size_t)l * 128 * 128;
        for (int idx = tid; idx < 2048; idx += 384) {
            int t = idx >> 8, s = (idx >> 6) & 3, ln = idx & 63;
            int lq = ln >> 4, lpp = ln & 15;
            *(bf16x8*)(bS + idx * 8) =
                *(const bf16x8*)(bpe + (size_t)(16 * t + lpp) * 128 + s * 32 + lq * 8);
        }
        if (tid < 128) {
            float et0 = ws[OFF_ET + l * 256 + tid];
            float et1 = ws[OFF_ET + l * 256 + 128 + tid];
            #pragma unroll
            for (int g = 0; g < KG; g++) {
                float pav = ws[OFF_PA + (size_t)(i0 + g) * 128 + tid];
                pe0S[g * 128 + tid] = pav + et0;
                pe1S[g * 128 + tid] = pav + et1;
            }
            wcS[tid] = We1[(l * 289 + 256) * 128 + tid];
        }
        if (tid < KG * 3) xT[tid] = Xc[(size_t)(i0 + tid / 3) * 3 + tid % 3];
        if (tid < KG) ciS[tid] = chain[i0 + tid];
    }

    int w = tid >> 6, lane = tid & 63;
    int quad = lane >> 4, lp = lane & 15;
    int jA = 16 * w + lp;                       // lane's fixed source row
    const short* pbrow = (const short*)(ws + OFF_PBH) + (size_t)(colbase + jA) * 128;
    bf16x8 pbv[4];
    #pragma unroll
    for (int s = 0; s < 4; s++) pbv[s] = *(const bf16x8*)(pbrow + s * 32 + quad * 8);
    float xr0 = Xc[(size_t)(colbase + jA) * 3 + 0];
    float xr1 = Xc[(size_t)(colbase + jA) * 3 + 1];
    float xr2 = Xc[(size_t)(colbase + jA) * 3 + 2];
    int cj = chain[colbase + jA];
    float be2r[8], wxr[8];
    #pragma unroll
    for (int t = 0; t < 8; t++) {
        int ch = 16 * t + lp;
        be2r[t] = be2[l * 128 + ch];
        wxr[t]  = Wx[l * 128 + ch];
    }
    // epilogue x hoists (waves 0..2 only use them)
    float ex0 = 0.f, ex1 = 0.f;
    if (w < 3) {
        ex0 = Xc[(size_t)(colbase + lane) * 3 + w];
        if (lane < 32) ex1 = Xc[(size_t)(colbase + lane + 64) * 3 + w];
    }
    __syncthreads();

    #pragma unroll
    for (int g = 0; g < KG; g++) {
        float rx = xT[g * 3 + 0] - xr0;
        float ry = xT[g * 3 + 1] - xr1;
        float rz = xT[g * 3 + 2] - xr2;
        float d2j = rx * rx + ry * ry + rz * rz;
        const float* peB = ((cj != ciS[g]) ? pe1S : pe0S) + g * 128;

        f32x4 acc[8];
        #pragma unroll
        for (int t = 0; t < 8; t++) acc[t] = (f32x4){0.f, 0.f, 0.f, 0.f};

        #pragma unroll
        for (int s = 0; s < 4; s++) {
            int kb = s * 32 + quad * 8;
            // vectorized LDS reads (b128 broadcast within quad)
            float4 p0 = *(const float4*)(peB + kb);
            float4 p1 = *(const float4*)(peB + kb + 4);
            float4 w0 = *(const float4*)(wcS + kb);
            float4 w1 = *(const float4*)(wcS + kb + 4);
            float pe[8] = {p0.x, p0.y, p0.z, p0.w, p1.x, p1.y, p1.z, p1.w};
            float wc[8] = {w0.x, w0.y, w0.z, w0.w, w1.x, w1.y, w1.z, w1.w};
            float z[8];
            #pragma unroll
            for (int e = 0; e < 8; e++)
                z[e] = silu(pe[e] + bf2f(pbv[s][e]) + d2j * wc[e]);
            bf16x8 af;
            #pragma unroll
            for (int e = 0; e < 8; e += 2) {
                short2 p = f2bf2(z[e], z[e + 1]);
                af[e] = p.x; af[e + 1] = p.y;
            }
            #pragma unroll
            for (int t = 0; t < 8; t++) {
                bf16x8 bf = *(const bf16x8*)(bS + ((t * 4 + s) * 64 + lane) * 8);
                acc[t] = __builtin_amdgcn_mfma_f32_16x16x32_bf16(af, bf, acc[t], 0, 0, 0);
            }
        }

        // epilogue: m2[row=16w+quad*4+r][chan=16t+lp]
        float cp[4] = {0.f, 0.f, 0.f, 0.f};
        #pragma unroll
        for (int t = 0; t < 8; t++) {
            float ag = 0.f;
            #pragma unroll
            for (int r = 0; r < 4; r++) {
                float m2 = silu(acc[t][r] + be2r[t]);
                ag += m2;
                cp[r] += m2 * wxr[t];
            }
            ag += __shfl_xor(ag, 16);
            ag += __shfl_xor(ag, 32);
            if (lane < 16) aggP[w * 128 + 16 * t + lp] = ag;
        }
        #pragma unroll
        for (int r = 0; r < 4; r++) {
            float v = cp[r];
            v += __shfl_xor(v, 1);
            v += __shfl_xor(v, 2);
            v += __shfl_xor(v, 4);
            v += __shfl_xor(v, 8);
            if (lp == 0) coefS[16 * w + quad * 4 + r] = v;
        }
        __syncthreads();

        if (tid < 128) {
            float s = 0.f;
            #pragma unroll
            for (int q = 0; q < 6; q++) s += aggP[q * 128 + tid];
            ws[OFF_AGG + (size_t)(i0 + g) * 128 + tid] = s;
        }
        if (w < 3) {
            float v = (xT[g * 3 + w] - ex0) * coefS[lane];
            if (lane < 32) v += (xT[g * 3 + w] - ex1) * coefS[lane + 64];
            #pragma unroll
            for (int o = 32; o > 0; o >>= 1) v += __shfl_down(v, o);
            if (lane == 0) ws[OFF_DX + (size_t)(i0 + g) * 3 + w] = v;
        }
        __syncthreads();
    }
}

// ----- K4s: node update row-split — grid (32, 6), 256 thr, 16 nodes/WG
// + pa/pb(l+1) (l<2) or loss (l==2, with 192-WG election final write-out)
__global__ void __launch_bounds__(256)
k4s_node_post(const float* __restrict__ bh1, const float* __restrict__ bh2,
              const float* __restrict__ be1, const float* __restrict__ bout,
              const float* __restrict__ H0, const float* __restrict__ X0,
              const float* __restrict__ H1, const float* __restrict__ X1,
              const int* __restrict__ gmask, const int* __restrict__ shiftp,
              int l, float* __restrict__ ws, float* __restrict__ out) {
    __shared__ short uS[16 * 136];
    __shared__ short hS[16 * 136];
    __shared__ float redE[4], redN[4];
    __shared__ float sxp, sxn, scnt;
    int rowbase = blockIdx.x * 96 + blockIdx.y * 16;
    int tid = threadIdx.x;
    int w = tid >> 6, lane = tid & 63;
    int quad = lane >> 4, lp = lane & 15;
    int nodeA = rowbase + lp;
    const short* b1 = (const short*)(ws + OFF_BH1) + (size_t)l * 128 * 256;
    const short* b2 = (const short*)(ws + OFF_BH2) + (size_t)l * 128 * 128;

    if (tid == 0) { sxp = 0.f; sxn = 0.f; scnt = 0.f; }
    if (tid < 48) {
        int node = rowbase + tid / 3, d = tid % 3;
        ws[OFF_X + (size_t)node * 3 + d] += ws[OFF_DX + (size_t)node * 3 + d];
    }

    // ---- GEMM1: [h|agg] K=256 -> u (silu); ct = 2w+i
    f32x4 acc[2];
    acc[0] = (f32x4){0.f, 0.f, 0.f, 0.f};
    acc[1] = (f32x4){0.f, 0.f, 0.f, 0.f};
    #pragma unroll
    for (int s = 0; s < 8; s++) {
        int kb = s * 32 + quad * 8;
        const float* src = (kb < 128) ? (ws + OFF_H + (size_t)nodeA * 128 + kb)
                                      : (ws + OFF_AGG + (size_t)nodeA * 128 + (kb - 128));
        bf16x8 af;
        #pragma unroll
        for (int e = 0; e < 8; e += 2) {
            short2 p = f2bf2(src[e], src[e + 1]);
            af[e] = p.x; af[e + 1] = p.y;
        }
        #pragma unroll
        for (int i = 0; i < 2; i++) {
            int ct = 2 * w + i;
            bf16x8 bf = *(const bf16x8*)(b1 + (size_t)(16 * ct + lp) * 256 + kb);
            acc[i] = __builtin_amdgcn_mfma_f32_16x16x32_bf16(af, bf, acc[i], 0, 0, 0);
        }
    }
    #pragma unroll
    for (int i = 0; i < 2; i++) {
        int ch = 16 * (2 * w + i) + lp;
        float bb1 = bh1[l * 128 + ch];
        #pragma unroll
        for (int r = 0; r < 4; r++)
            uS[(quad * 4 + r) * 136 + ch] = f2bf(silu(acc[i][r] + bb1));
    }
    __syncthreads();

    // ---- GEMM2: u @ Wh2 -> h += ; hS = bf16(h)
    acc[0] = (f32x4){0.f, 0.f, 0.f, 0.f};
    acc[1] = (f32x4){0.f, 0.f, 0.f, 0.f};
    #pragma unroll
    for (int s = 0; s < 4; s++) {
        int kb = s * 32 + quad * 8;
        bf16x8 af = *(const bf16x8*)(uS + lp * 136 + kb);
        #pragma unroll
        for (int i = 0; i < 2; i++) {
            int ct = 2 * w + i;
            bf16x8 bf = *(const bf16x8*)(b2 + (size_t)(16 * ct + lp) * 128 + kb);
            acc[i] = __builtin_amdgcn_mfma_f32_16x16x32_bf16(af, bf, acc[i], 0, 0, 0);
        }
    }
    #pragma unroll
    for (int i = 0; i < 2; i++) {
        int ch = 16 * (2 * w + i) + lp;
        float bb2 = bh2[l * 128 + ch];
        #pragma unroll
        for (int r = 0; r < 4; r++) {
            int row = quad * 4 + r;
            size_t off = OFF_H + (size_t)(rowbase + row) * 128 + ch;
            float h = ws[off] + acc[i][r] + bb2;
            ws[off] = h;
            hS[row * 136 + ch] = f2bf(h);
        }
    }
    __syncthreads();

    if (l < 2) {
        // ---- GEMM3: pa/pb for layer l+1, N=256 (ct4 = 4w+i)
        const short* bab = (const short*)(ws + OFF_BAB) + (size_t)(l + 1) * 256 * 128;
        f32x4 acc4[4];
        #pragma unroll
        for (int i = 0; i < 4; i++) acc4[i] = (f32x4){0.f, 0.f, 0.f, 0.f};
        #pragma unroll
        for (int s = 0; s < 4; s++) {
            int kb = s * 32 + quad * 8;
            bf16x8 af = *(const bf16x8*)(hS + lp * 136 + kb);
            #pragma unroll
            for (int i = 0; i < 4; i++) {
                int ct4 = 4 * w + i;
                bf16x8 bf = *(const bf16x8*)(bab + (size_t)(16 * ct4 + lp) * 128 + kb);
                acc4[i] = __builtin_amdgcn_mfma_f32_16x16x32_bf16(af, bf, acc4[i], 0, 0, 0);
            }
        }
        short* pbh = (short*)(ws + OFF_PBH);
        #pragma unroll
        for (int i = 0; i < 4; i++) {
            int ct4 = 4 * w + i;
            #pragma unroll
            for (int r = 0; r < 4; r++) {
                int node = rowbase + quad * 4 + r;
                if (ct4 < 8) {
                    int ch = 16 * ct4 + lp;
                    ws[OFF_PA + (size_t)node * 128 + ch] = acc4[i][r] + be1[(l + 1) * 128 + ch];
                } else {
                    int ch = 16 * (ct4 - 8) + lp;
                    pbh[(size_t)node * 128 + ch] = f2bf(acc4[i][r]);
                }
            }
        }
    } else {
        // ---- GEMM3: v = h @ Wout^T (N=64, ct=w) + loss reduction + final out
        const short* bwo = (const short*)(ws + OFF_BWO);
        f32x4 accv = (f32x4){0.f, 0.f, 0.f, 0.f};
        #pragma unroll
        for (int s = 0; s < 4; s++) {
            int kb = s * 32 + quad * 8;
            bf16x8 af = *(const bf16x8*)(hS + lp * 136 + kb);
            bf16x8 bf = *(const bf16x8*)(bwo + (size_t)(16 * w + lp) * 128 + kb);
            accv = __builtin_amdgcn_mfma_f32_16x16x32_bf16(af, bf, accv, 0, 0, 0);
        }
        int s = shiftp[0] % NN; if (s < 0) s += NN;
        int col = 16 * w + lp;
        float bo = bout[col];
        float ep = 0.f, en = 0.f;
        #pragma unroll
        for (int r = 0; r < 4; r++) {
            int row = rowbase + quad * 4 + r;
            if (gmask[row] != 0) {
                int ip = row + s; if (ip >= NN) ip -= NN;
                float v  = accv[r] + bo;
                float tp = H1[(size_t)row * 64 + col] - H0[(size_t)row * 64 + col];
                float tn = H1[(size_t)ip * 64 + col]  - H0[(size_t)ip * 64 + col];
                float dp = v - tp, dn = v - tn;
                ep += dp * dp;
                en += dn * dn;
            }
        }
        #pragma unroll
        for (int o = 1; o < 64; o <<= 1) {
            ep += __shfl_xor(ep, o);
            en += __shfl_xor(en, o);
        }
        if (lane == 0) { redE[w] = ep; redN[w] = en; }

        if (tid < 16) {
            int node = rowbase + tid;
            if (gmask[node] != 0) {
                int ip = node + s; if (ip >= NN) ip -= NN;
                float xp = 0.f, xn = 0.f;
                #pragma unroll
                for (int d = 0; d < 3; d++) {
                    float xv  = ws[OFF_X + (size_t)node * 3 + d];
                    float tpx = X1[(size_t)node * 3 + d] - X0[(size_t)node * 3 + d];
                    float tnx = X1[(size_t)ip * 3 + d]   - X0[(size_t)ip * 3 + d];
                    xp += (xv - tpx) * (xv - tpx);
                    xn += (xv - tnx) * (xv - tnx);
                }
                atomicAdd(&sxp, xp);
                atomicAdd(&sxn, xn);
                atomicAdd(&scnt, 1.0f);
            }
        }
        __syncthreads();
        if (tid == 0) {
            float eT = redE[0] + redE[1] + redE[2] + redE[3];
            float nT = redN[0] + redN[1] + redN[2] + redN[3];
            float* acc0 = ws + OFF_ACC;
            atomicAdd(acc0 + 0, eT);
            atomicAdd(acc0 + 2, nT);
            atomicAdd(acc0 + 1, sxp);
            atomicAdd(acc0 + 3, sxn);
            atomicAdd(acc0 + 4, scnt);
            // ---- final election among the 192 l==2 WGs: write out
            __threadfence();
            unsigned o2 = atomicAdd((unsigned*)(ws + OFF_CNT) + 96, 1u);
            if (o2 == 191u) {
                __threadfence();
                float a0 = atomicAdd(acc0 + 0, 0.0f);
                float a1 = atomicAdd(acc0 + 1, 0.0f);
                float a2 = atomicAdd(acc0 + 2, 0.0f);
                float a3 = atomicAdd(acc0 + 3, 0.0f);
                float a4 = atomicAdd(acc0 + 4, 0.0f);
                float msum = a4 + 1e-8f;
                float lhp = a0 / msum, lxp = a1 / msum;
                float lhn = a2 / msum, lxn = a3 / msum;
                out[0] = lhp - 0.05f * lhn;
                out[1] = lxp - 0.05f * lxn;
                out[2] = lhp;
                out[3] = lxp;
                out[4] = lhn;
                out[5] = lxn;
            }
        }
    }
}

extern "C" void kernel_launch(void* const* d_in, const int* in_sizes, int n_in,
                              void* d_out, int out_size, void* d_ws, size_t ws_size,
                              hipStream_t stream) {
    (void)in_sizes; (void)n_in; (void)out_size; (void)ws_size;
    const float* H0   = (const float*)d_in[0];
    const float* X0   = (const float*)d_in[1];
    const float* H1   = (const float*)d_in[2];
    const float* X1   = (const float*)d_in[3];
    const float* cond = (const float*)d_in[4];
    const float* tg   = (const float*)d_in[5];
    const float* Wi1  = (const float*)d_in[6];
    const float* bi1  = (const float*)d_in[7];
    const float* Wi2  = (const float*)d_in[8];
    const float* bi2  = (const float*)d_in[9];
    const float* Wi3  = (const float*)d_in[10];
    const float* bi3  = (const float*)d_in[11];
    const float* etab = (const float*)d_in[12];
    const float* We1  = (const float*)d_in[13];
    const float* be1  = (const float*)d_in[14];
    const float* We2  = (const float*)d_in[15];
    const float* be2  = (const float*)d_in[16];
    const float* Wx   = (const float*)d_in[17];
    const float* Wh1  = (const float*)d_in[18];
    const float* bh1  = (const float*)d_in[19];
    const float* Wh2  = (const float*)d_in[20];
    const float* bh2  = (const float*)d_in[21];
    const float* Wout = (const float*)d_in[22];
    const float* bout = (const float*)d_in[23];
    const int* chain   = (const int*)d_in[25];
    const int* gmask   = (const int*)d_in[26];
    const int* lengths = (const int*)d_in[27];
    const int* shiftp  = (const int*)d_in[28];
    float* ws  = (float*)d_ws;
    float* out = (float*)d_out;

    k0_all<<<1473, 256, 0, stream>>>(etab, We1, lengths, We2, Wh1, Wh2,
                                     Wout, Wi1, Wi2, Wi3, ws);
    k1s_node_init<<<dim3(NBATCH, 6), 256, 0, stream>>>(H0, X0, H1, X1, cond, tg,
                                                       bi1, bi2, bi3, be1, gmask, ws);
    for (int l = 0; l < 3; l++) {
        k3v_edge<<<NN / KG, 384, 0, stream>>>(We1, Wx, be2, chain, l, ws);
        k4s_node_post<<<dim3(NBATCH, 6), 256, 0, stream>>>(bh1, bh2, be1, bout,
                                                           H0, X0, H1, X1, gmask, shiftp,
                                                           l, ws, out);
    }
}